// Round 1
// baseline (2573.627 us; speedup 1.0000x reference)
//
#include <hip/hip_runtime.h>
#include <math.h>

// Problem constants (B=1)
#define H_    16
#define DR_   64
#define HD_   128
#define D_    2048
#define SX_   2048
#define SY_   512
#define SZ_   2560
#define NQKV_ 6144          // 3*H*HD
#define EPS_  1e-6f
#define ATTN_SCALE 0.07216878364870323f   // 1/sqrt(2*DR+DN) = 1/sqrt(192)

// ---------------- kernel 1: modulation GEMV  (mq = mod@Wmod_q^T + b, mkv likewise) ----------------
__global__ __launch_bounds__(256) void mod_gemv_kernel(
    const float* __restrict__ mod,
    const float* __restrict__ Wq, const float* __restrict__ bq,
    const float* __restrict__ Wkv, const float* __restrict__ bkv,
    float* __restrict__ mq, float* __restrict__ mkv)
{
    int t = threadIdx.x;
    int row = blockIdx.x * 4 + (t >> 6);   // 0..12287, one wave per output
    int lane = t & 63;
    const float* W; const float* b; float* out; int r;
    if (row < NQKV_) { W = Wq;  b = bq;  out = mq;  r = row; }
    else             { W = Wkv; b = bkv; out = mkv; r = row - NQKV_; }
    const float* wr = W + (size_t)r * D_;
    float s = 0.f;
    for (int k = lane; k < D_; k += 64) s += wr[k] * mod[k];
#pragma unroll
    for (int m = 32; m >= 1; m >>= 1) s += __shfl_xor(s, m);
    if (lane == 0) out[r] = s + b[r];
}

// ---------------- kernel 2: LayerNorm + modulation:  xm = (1+scale)*ln(x) + bias ----------------
__global__ __launch_bounds__(256) void ln_mod_kernel(
    const float* __restrict__ x, const float* __restrict__ y,
    const float* __restrict__ mq, const float* __restrict__ mkv,
    float* __restrict__ xm)
{
    __shared__ float red[8];
    int s = blockIdx.x, t = threadIdx.x;
    const float* src; const float* mv;
    if (s < SX_) { src = x + (size_t)s * D_;          mv = mq; }
    else         { src = y + (size_t)(s - SX_) * D_;  mv = mkv; }
    float a[8];
    *(float4*)&a[0] = *(const float4*)(src + t * 8);
    *(float4*)&a[4] = *(const float4*)(src + t * 8 + 4);
    float sum = 0.f, ssq = 0.f;
#pragma unroll
    for (int i = 0; i < 8; ++i) { sum += a[i]; ssq += a[i] * a[i]; }
#pragma unroll
    for (int m = 32; m >= 1; m >>= 1) { sum += __shfl_xor(sum, m); ssq += __shfl_xor(ssq, m); }
    if ((t & 63) == 0) { red[t >> 6] = sum; red[4 + (t >> 6)] = ssq; }
    __syncthreads();
    float tot  = red[0] + red[1] + red[2] + red[3];
    float totq = red[4] + red[5] + red[6] + red[7];
    float mean = tot * (1.f / (float)D_);
    float var  = totq * (1.f / (float)D_) - mean * mean;
    float inv  = rsqrtf(var + EPS_);
    float* dst = xm + (size_t)s * D_;
    float o[8];
#pragma unroll
    for (int i = 0; i < 8; ++i) {
        int c = t * 8 + i;
        float v = (a[i] - mean) * inv;
        o[i] = (1.f + mv[D_ + c]) * v + mv[c];   // scale at [D..2D), bias at [0..D)
    }
    *(float4*)(dst + t * 8)     = *(float4*)&o[0];
    *(float4*)(dst + t * 8 + 4) = *(float4*)&o[4];
}

// ---------------- kernel 3: tiled f32 GEMM  C = A @ W^T + b, optional gate+residual epilogue -----
// A: (SZ_, 2048) row-major. W: (N, 2048) row-major. 64x64 tile, BK=16, 4x4 per thread.
// Rows < SX_ use (Wx,bx), rows >= SX_ use (Wy,by). 2048 % 64 == 0 so tiles never straddle.
__global__ __launch_bounds__(256) void gemm_kernel(
    const float* __restrict__ A,
    const float* __restrict__ Wx, const float* __restrict__ bx,
    const float* __restrict__ Wy, const float* __restrict__ by,
    float* __restrict__ C, int N,
    const float* __restrict__ gx, const float* __restrict__ gy,
    const float* __restrict__ rx, const float* __restrict__ ry,
    int doEpi)
{
    __shared__ __align__(16) float As[16][64];   // transposed tiles: [k][m]
    __shared__ __align__(16) float Ws[16][64];   // [k][n]
    int m0 = blockIdx.y * 64, n0 = blockIdx.x * 64;
    const float* W  = (m0 < SX_) ? Wx : Wy;
    const float* bb = (m0 < SX_) ? bx : by;
    int t = threadIdx.x;
    int ar = t >> 2, ac = (t & 3) * 4;   // staging: row t/4, 4 k's
    int tx = t & 15, ty = t >> 4;        // compute: 16x16 threads, 4x4 each
    float acc[4][4] = {};
    const float* Ap = A + (size_t)(m0 + ar) * D_ + ac;
    const float* Wp = W + (size_t)(n0 + ar) * D_ + ac;
    for (int k0 = 0; k0 < D_; k0 += 16) {
        float4 av = *(const float4*)(Ap + k0);
        float4 wv = *(const float4*)(Wp + k0);
        __syncthreads();
        As[ac + 0][ar] = av.x; As[ac + 1][ar] = av.y; As[ac + 2][ar] = av.z; As[ac + 3][ar] = av.w;
        Ws[ac + 0][ar] = wv.x; Ws[ac + 1][ar] = wv.y; Ws[ac + 2][ar] = wv.z; Ws[ac + 3][ar] = wv.w;
        __syncthreads();
#pragma unroll
        for (int kk = 0; kk < 16; ++kk) {
            float4 af = *(const float4*)&As[kk][ty * 4];
            float4 wf = *(const float4*)&Ws[kk][tx * 4];
            float a4[4] = {af.x, af.y, af.z, af.w};
            float w4[4] = {wf.x, wf.y, wf.z, wf.w};
#pragma unroll
            for (int i = 0; i < 4; ++i)
#pragma unroll
                for (int jj = 0; jj < 4; ++jj)
                    acc[i][jj] += a4[i] * w4[jj];
        }
    }
#pragma unroll
    for (int i = 0; i < 4; ++i) {
        int row = m0 + ty * 4 + i;
        int col = n0 + tx * 4;
        float o[4];
#pragma unroll
        for (int jj = 0; jj < 4; ++jj) o[jj] = acc[i][jj] + bb[col + jj];
        if (doEpi) {
            const float* g    = (row < SX_) ? gx : gy;
            const float* rres = (row < SX_) ? rx + (size_t)row * N : ry + (size_t)(row - SX_) * N;
#pragma unroll
            for (int jj = 0; jj < 4; ++jj) o[jj] = o[jj] * g[col + jj] + rres[col + jj];
        }
        *(float4*)(C + (size_t)row * N + col) = *(float4*)&o[0];
    }
}

// ---------------- kernel 4: RMS-norm + RoPE + head-major transpose --------------------------------
// qkv row s = [q(2048) | k(2048) | v(2048)], head h at cols h*128.. . Output layout [h][s][d].
// Stored head dim: [0..63] = own-modality-rotated rope, [64..127] = nope.
// Attention scale folded into q (rotation commutes with uniform scale).
__global__ __launch_bounds__(256) void qkv_transform_kernel(
    const float* __restrict__ qkv,
    const float* __restrict__ fx, const float* __restrict__ fy,
    const float* __restrict__ wq, const float* __restrict__ wk,
    float* __restrict__ qh, float* __restrict__ kh, float* __restrict__ vh)
{
    int t = threadIdx.x;
    int gid = blockIdx.x * 4 + (t >> 6);   // one wave per (s,h)
    int lane = t & 63;
    int s = gid >> 4;     // / H_
    int h = gid & 15;
    const float* base = qkv + (size_t)s * NQKV_ + h * HD_;
    int d = lane * 2;     // lanes 0..31: rope pair (2l,2l+1); lanes 32..63: nope pair
    float2 qv = *(const float2*)(base + d);
    float2 kv = *(const float2*)(base + 2048 + d);
    float2 vv = *(const float2*)(base + 4096 + d);
    float sq = qv.x * qv.x + qv.y * qv.y;
    float sk = kv.x * kv.x + kv.y * kv.y;
#pragma unroll
    for (int m = 32; m >= 1; m >>= 1) { sq += __shfl_xor(sq, m); sk += __shfl_xor(sk, m); }
    float qs = rsqrtf(sq * (1.f / 128.f) + EPS_) * ATTN_SCALE;
    float ks = rsqrtf(sk * (1.f / 128.f) + EPS_);
    float q0 = qv.x * qs * wq[d], q1 = qv.y * qs * wq[d + 1];
    float k0 = kv.x * ks * wk[d], k1 = kv.y * ks * wk[d + 1];
    if (lane < 32) {  // rope dims
        const float* f = (s < SX_) ? fx + (size_t)s * DR_ + d
                                   : fy + (size_t)(s - SX_) * DR_ + d;
        float cs = f[0], sn = f[1];
        float o0 = q0 * cs - q1 * sn, o1 = q0 * sn + q1 * cs;
        q0 = o0; q1 = o1;
        o0 = k0 * cs - k1 * sn; o1 = k0 * sn + k1 * cs;
        k0 = o0; k1 = o1;
    }
    size_t off = ((size_t)h * SZ_ + s) * HD_ + d;
    qh[off] = q0; qh[off + 1] = q1;
    kh[off] = k0; kh[off + 1] = k1;
    vh[off] = vv.x; vh[off + 1] = vv.y;
}

// ---------------- kernel 5: flash attention (f32), 32 queries x 32 keys tiles ---------------------
// Same-modality tiles: full 128-dot. Cross-modality: nope-only (dims 64..127) — exact, since the
// reference's rope slots are zero across modalities. PADW=132 makes all inner LDS reads
// conflict-free (8 distinct bank-quads, 8-lane broadcasts).
__global__ __launch_bounds__(256) void attn_kernel(
    const float* __restrict__ qh, const float* __restrict__ kh,
    const float* __restrict__ vh, float* __restrict__ z)
{
    const int PADW = 132;
    __shared__ __align__(16) float Qs[32][PADW];
    __shared__ __align__(16) float Ks[32][PADW];
    __shared__ __align__(16) float Vs[32][PADW];
    int h = blockIdx.y;
    int bq = blockIdx.x * 32;
    int t = threadIdx.x;
    const float* qb = qh + (size_t)h * SZ_ * HD_;
    const float* kb = kh + (size_t)h * SZ_ * HD_;
    const float* vb = vh + (size_t)h * SZ_ * HD_;
#pragma unroll
    for (int i = 0; i < 4; ++i) {          // stage Q once (scale pre-folded)
        int idx = t + 256 * i;
        int r = idx >> 5, c = (idx & 31) * 4;
        *(float4*)&Qs[r][c] = *(const float4*)(qb + (size_t)(bq + r) * HD_ + c);
    }
    int qi = t >> 3, j = t & 7;            // row 0..31, lane-in-rowgroup 0..7
    int wbase = (t & 63) & 56;             // wave-local row-group base for shfl
    float4 acc[4];
#pragma unroll
    for (int k = 0; k < 4; ++k) acc[k] = make_float4(0.f, 0.f, 0.f, 0.f);
    float mold = -INFINITY, l = 0.f;
    bool qmY = (bq >= SX_);
    for (int t0 = 0; t0 < SZ_; t0 += 32) {
        __syncthreads();                    // prev PV done -> safe to restage K/V
#pragma unroll
        for (int i = 0; i < 4; ++i) {
            int idx = t + 256 * i;
            int r = idx >> 5, c = (idx & 31) * 4;
            *(float4*)&Ks[r][c] = *(const float4*)(kb + (size_t)(t0 + r) * HD_ + c);
            *(float4*)&Vs[r][c] = *(const float4*)(vb + (size_t)(t0 + r) * HD_ + c);
        }
        __syncthreads();
        bool same = (qmY == (t0 >= SX_));
        float sacc[4] = {0.f, 0.f, 0.f, 0.f};   // 4 keys per thread: j, j+8, j+16, j+24
        for (int d = same ? 0 : 64; d < HD_; d += 4) {
            float4 qv = *(const float4*)&Qs[qi][d];
#pragma unroll
            for (int m = 0; m < 4; ++m) {
                float4 kv = *(const float4*)&Ks[j + 8 * m][d];
                sacc[m] += qv.x * kv.x + qv.y * kv.y + qv.z * kv.z + qv.w * kv.w;
            }
        }
        // online softmax, entirely in registers (replicated across the 8-lane row group)
        float gm = fmaxf(fmaxf(sacc[0], sacc[1]), fmaxf(sacc[2], sacc[3]));
#pragma unroll
        for (int m = 4; m >= 1; m >>= 1) gm = fmaxf(gm, __shfl_xor(gm, m));
        float mnew = fmaxf(mold, gm);
        float corr = __expf(mold - mnew);       // first tile: exp(-inf)=0
        float p[4]; float rs = 0.f;
#pragma unroll
        for (int m = 0; m < 4; ++m) { p[m] = __expf(sacc[m] - mnew); rs += p[m]; }
#pragma unroll
        for (int m = 4; m >= 1; m >>= 1) rs += __shfl_xor(rs, m);
        l = l * corr + rs;
        mold = mnew;
#pragma unroll
        for (int k = 0; k < 4; ++k) {
            acc[k].x *= corr; acc[k].y *= corr; acc[k].z *= corr; acc[k].w *= corr;
        }
        // PV: thread (qi,j) owns dims {j*4 + 32k .. +3}; P broadcast via wave shuffle
#pragma unroll
        for (int kj = 0; kj < 32; ++kj) {
            float pp = __shfl(p[kj >> 3], wbase + (kj & 7));
#pragma unroll
            for (int k = 0; k < 4; ++k) {
                const float4 vv = *(const float4*)&Vs[kj][j * 4 + 32 * k];
                acc[k].x += pp * vv.x; acc[k].y += pp * vv.y;
                acc[k].z += pp * vv.z; acc[k].w += pp * vv.w;
            }
        }
    }
    float invl = 1.f / l;
    float* zp = z + (size_t)(bq + qi) * D_ + h * HD_ + j * 4;
#pragma unroll
    for (int k = 0; k < 4; ++k) {
        float4 o = make_float4(acc[k].x * invl, acc[k].y * invl, acc[k].z * invl, acc[k].w * invl);
        *(float4*)(zp + 32 * k) = o;
    }
}

extern "C" void kernel_launch(void* const* d_in, const int* in_sizes, int n_in,
                              void* d_out, int out_size, void* d_ws, size_t ws_size,
                              hipStream_t stream) {
    const float* x    = (const float*)d_in[0];
    const float* y    = (const float*)d_in[1];
    const float* mod  = (const float*)d_in[2];
    const float* fx   = (const float*)d_in[3];
    const float* fy   = (const float*)d_in[4];
    // d_in[5], d_in[6]: masks — all-true in this problem, ignored
    const float* Wqx  = (const float*)d_in[7];
    const float* bqx  = (const float*)d_in[8];
    const float* Wqy  = (const float*)d_in[9];
    const float* bqy  = (const float*)d_in[10];
    const float* Wout = (const float*)d_in[11];
    const float* bout = (const float*)d_in[12];
    const float* wq   = (const float*)d_in[13];
    const float* wk   = (const float*)d_in[14];
    const float* Wmq  = (const float*)d_in[15];
    const float* bmq  = (const float*)d_in[16];
    const float* Wmk  = (const float*)d_in[17];
    const float* bmk  = (const float*)d_in[18];

    // workspace layout (floats); total ≈ 146.8 MB
    float* ws   = (float*)d_ws;
    float* mq   = ws;                              // 6144  [bias_x|scale_x|gate_x]
    float* mkv  = mq  + NQKV_;                     // 6144
    float* xm   = mkv + NQKV_;                     // SZ*D   (modulated LN; later reused as z)
    float* qkv  = xm  + (size_t)SZ_ * D_;          // SZ*6144
    float* qh   = qkv + (size_t)SZ_ * NQKV_;       // H*SZ*HD
    float* kh   = qh  + (size_t)H_ * SZ_ * HD_;
    float* vh   = kh  + (size_t)H_ * SZ_ * HD_;
    float* z    = xm;                              // alias: xm dead after QKV GEMM
    float* out  = (float*)d_out;

    hipLaunchKernelGGL(mod_gemv_kernel, dim3(2 * NQKV_ / 4), dim3(256), 0, stream,
                       mod, Wmq, bmq, Wmk, bmk, mq, mkv);
    hipLaunchKernelGGL(ln_mod_kernel, dim3(SZ_), dim3(256), 0, stream,
                       x, y, mq, mkv, xm);
    hipLaunchKernelGGL(gemm_kernel, dim3(NQKV_ / 64, SZ_ / 64), dim3(256), 0, stream,
                       xm, Wqx, bqx, Wqy, bqy, qkv, NQKV_,
                       (const float*)nullptr, (const float*)nullptr,
                       (const float*)nullptr, (const float*)nullptr, 0);
    hipLaunchKernelGGL(qkv_transform_kernel, dim3(SZ_ * H_ / 4), dim3(256), 0, stream,
                       qkv, fx, fy, wq, wk, qh, kh, vh);
    hipLaunchKernelGGL(attn_kernel, dim3(SZ_ / 32, H_), dim3(256), 0, stream,
                       qh, kh, vh, z);
    hipLaunchKernelGGL(gemm_kernel, dim3(D_ / 64, SZ_ / 64), dim3(256), 0, stream,
                       z, Wout, bout, Wout, bout, out, D_,
                       mq + 2 * D_, mkv + 2 * D_, x, y, 1);
}

// Round 2
// 1439.681 us; speedup vs baseline: 1.7876x; 1.7876x over previous
//
#include <hip/hip_runtime.h>
#include <math.h>

// Problem constants (B=1)
#define H_    16
#define DR_   64
#define HD_   128
#define D_    2048
#define SX_   2048
#define SY_   512
#define SZ_   2560
#define NQKV_ 6144          // 3*H*HD
#define EPS_  1e-6f
#define ATTN_SCALE 0.07216878364870323f   // 1/sqrt(2*DR+DN) = 1/sqrt(192)

typedef __attribute__((ext_vector_type(8)))  short short8;   // bf16x8 MFMA frag (4 VGPR)
typedef __attribute__((ext_vector_type(16))) float f32x16;   // 32x32 MFMA accum

__device__ __forceinline__ unsigned short f2bf(float f) {
    unsigned u = __builtin_bit_cast(unsigned, f);
    u += 0x7FFF + ((u >> 16) & 1);          // RNE
    return (unsigned short)(u >> 16);
}

__device__ __forceinline__ unsigned cvtpk_bf16(float lo, float hi) {
    unsigned r;
    asm volatile("v_cvt_pk_bf16_f32 %0, %1, %2" : "=v"(r) : "v"(lo), "v"(hi));
    return r;
}

// Build PV A/B fragment (16 keys) from 8 per-lane P values (C-reg order) via permlane32_swap.
__device__ __forceinline__ short8 mkfrag(const float* p) {
    unsigned a01 = cvtpk_bf16(p[0], p[1]);
    unsigned a23 = cvtpk_bf16(p[2], p[3]);
    unsigned a45 = cvtpk_bf16(p[4], p[5]);
    unsigned a67 = cvtpk_bf16(p[6], p[7]);
    asm volatile("v_permlane32_swap_b32 %0, %1" : "+v"(a01), "+v"(a45));
    asm volatile("v_permlane32_swap_b32 %0, %1" : "+v"(a23), "+v"(a67));
    union { unsigned u[4]; short8 s; } r;
    r.u[0] = a01; r.u[1] = a23; r.u[2] = a45; r.u[3] = a67;
    return r.s;
}

// ---------------- kernel 1: modulation GEMV ----------------
__global__ __launch_bounds__(256) void mod_gemv_kernel(
    const float* __restrict__ mod,
    const float* __restrict__ Wq, const float* __restrict__ bq,
    const float* __restrict__ Wkv, const float* __restrict__ bkv,
    float* __restrict__ mq, float* __restrict__ mkv)
{
    int t = threadIdx.x;
    int row = blockIdx.x * 4 + (t >> 6);
    int lane = t & 63;
    const float* W; const float* b; float* out; int r;
    if (row < NQKV_) { W = Wq;  b = bq;  out = mq;  r = row; }
    else             { W = Wkv; b = bkv; out = mkv; r = row - NQKV_; }
    const float* wr = W + (size_t)r * D_;
    float s = 0.f;
    for (int k = lane; k < D_; k += 64) s += wr[k] * mod[k];
#pragma unroll
    for (int m = 32; m >= 1; m >>= 1) s += __shfl_xor(s, m);
    if (lane == 0) out[r] = s + b[r];
}

// ---------------- kernel 2: LayerNorm + modulation ----------------
__global__ __launch_bounds__(256) void ln_mod_kernel(
    const float* __restrict__ x, const float* __restrict__ y,
    const float* __restrict__ mq, const float* __restrict__ mkv,
    float* __restrict__ xm)
{
    __shared__ float red[8];
    int s = blockIdx.x, t = threadIdx.x;
    const float* src; const float* mv;
    if (s < SX_) { src = x + (size_t)s * D_;          mv = mq; }
    else         { src = y + (size_t)(s - SX_) * D_;  mv = mkv; }
    float a[8];
    *(float4*)&a[0] = *(const float4*)(src + t * 8);
    *(float4*)&a[4] = *(const float4*)(src + t * 8 + 4);
    float sum = 0.f, ssq = 0.f;
#pragma unroll
    for (int i = 0; i < 8; ++i) { sum += a[i]; ssq += a[i] * a[i]; }
#pragma unroll
    for (int m = 32; m >= 1; m >>= 1) { sum += __shfl_xor(sum, m); ssq += __shfl_xor(ssq, m); }
    if ((t & 63) == 0) { red[t >> 6] = sum; red[4 + (t >> 6)] = ssq; }
    __syncthreads();
    float tot  = red[0] + red[1] + red[2] + red[3];
    float totq = red[4] + red[5] + red[6] + red[7];
    float mean = tot * (1.f / (float)D_);
    float var  = totq * (1.f / (float)D_) - mean * mean;
    float inv  = rsqrtf(var + EPS_);
    float* dst = xm + (size_t)s * D_;
    float o[8];
#pragma unroll
    for (int i = 0; i < 8; ++i) {
        int c = t * 8 + i;
        float v = (a[i] - mean) * inv;
        o[i] = (1.f + mv[D_ + c]) * v + mv[c];
    }
    *(float4*)(dst + t * 8)     = *(float4*)&o[0];
    *(float4*)(dst + t * 8 + 4) = *(float4*)&o[4];
}

// ---------------- kernel 3: tiled f32 GEMM (unchanged) ----------------
__global__ __launch_bounds__(256) void gemm_kernel(
    const float* __restrict__ A,
    const float* __restrict__ Wx, const float* __restrict__ bx,
    const float* __restrict__ Wy, const float* __restrict__ by,
    float* __restrict__ C, int N,
    const float* __restrict__ gx, const float* __restrict__ gy,
    const float* __restrict__ rx, const float* __restrict__ ry,
    int doEpi)
{
    __shared__ __align__(16) float As[16][64];
    __shared__ __align__(16) float Ws[16][64];
    int m0 = blockIdx.y * 64, n0 = blockIdx.x * 64;
    const float* W  = (m0 < SX_) ? Wx : Wy;
    const float* bb = (m0 < SX_) ? bx : by;
    int t = threadIdx.x;
    int ar = t >> 2, ac = (t & 3) * 4;
    int tx = t & 15, ty = t >> 4;
    float acc[4][4] = {};
    const float* Ap = A + (size_t)(m0 + ar) * D_ + ac;
    const float* Wp = W + (size_t)(n0 + ar) * D_ + ac;
    for (int k0 = 0; k0 < D_; k0 += 16) {
        float4 av = *(const float4*)(Ap + k0);
        float4 wv = *(const float4*)(Wp + k0);
        __syncthreads();
        As[ac + 0][ar] = av.x; As[ac + 1][ar] = av.y; As[ac + 2][ar] = av.z; As[ac + 3][ar] = av.w;
        Ws[ac + 0][ar] = wv.x; Ws[ac + 1][ar] = wv.y; Ws[ac + 2][ar] = wv.z; Ws[ac + 3][ar] = wv.w;
        __syncthreads();
#pragma unroll
        for (int kk = 0; kk < 16; ++kk) {
            float4 af = *(const float4*)&As[kk][ty * 4];
            float4 wf = *(const float4*)&Ws[kk][tx * 4];
            float a4[4] = {af.x, af.y, af.z, af.w};
            float w4[4] = {wf.x, wf.y, wf.z, wf.w};
#pragma unroll
            for (int i = 0; i < 4; ++i)
#pragma unroll
                for (int jj = 0; jj < 4; ++jj)
                    acc[i][jj] += a4[i] * w4[jj];
        }
    }
#pragma unroll
    for (int i = 0; i < 4; ++i) {
        int row = m0 + ty * 4 + i;
        int col = n0 + tx * 4;
        float o[4];
#pragma unroll
        for (int jj = 0; jj < 4; ++jj) o[jj] = acc[i][jj] + bb[col + jj];
        if (doEpi) {
            const float* g    = (row < SX_) ? gx : gy;
            const float* rres = (row < SX_) ? rx + (size_t)row * N : ry + (size_t)(row - SX_) * N;
#pragma unroll
            for (int jj = 0; jj < 4; ++jj) o[jj] = o[jj] * g[col + jj] + rres[col + jj];
        }
        *(float4*)(C + (size_t)row * N + col) = *(float4*)&o[0];
    }
}

// ---------------- kernel 4: RMS + RoPE + head-major transpose, bf16 out ----------------
__global__ __launch_bounds__(256) void qkv_transform_kernel(
    const float* __restrict__ qkv,
    const float* __restrict__ fx, const float* __restrict__ fy,
    const float* __restrict__ wq, const float* __restrict__ wk,
    unsigned short* __restrict__ qh, unsigned short* __restrict__ kh,
    unsigned short* __restrict__ vh)
{
    int t = threadIdx.x;
    int gid = blockIdx.x * 4 + (t >> 6);
    int lane = t & 63;
    int s = gid >> 4;
    int h = gid & 15;
    const float* base = qkv + (size_t)s * NQKV_ + h * HD_;
    int d = lane * 2;
    float2 qv = *(const float2*)(base + d);
    float2 kv = *(const float2*)(base + 2048 + d);
    float2 vv = *(const float2*)(base + 4096 + d);
    float sq = qv.x * qv.x + qv.y * qv.y;
    float sk = kv.x * kv.x + kv.y * kv.y;
#pragma unroll
    for (int m = 32; m >= 1; m >>= 1) { sq += __shfl_xor(sq, m); sk += __shfl_xor(sk, m); }
    float qs = rsqrtf(sq * (1.f / 128.f) + EPS_) * ATTN_SCALE;
    float ks = rsqrtf(sk * (1.f / 128.f) + EPS_);
    float q0 = qv.x * qs * wq[d], q1 = qv.y * qs * wq[d + 1];
    float k0 = kv.x * ks * wk[d], k1 = kv.y * ks * wk[d + 1];
    if (lane < 32) {
        const float* f = (s < SX_) ? fx + (size_t)s * DR_ + d
                                   : fy + (size_t)(s - SX_) * DR_ + d;
        float cs = f[0], sn = f[1];
        float o0 = q0 * cs - q1 * sn, o1 = q0 * sn + q1 * cs;
        q0 = o0; q1 = o1;
        o0 = k0 * cs - k1 * sn; o1 = k0 * sn + k1 * cs;
        k0 = o0; k1 = o1;
    }
    size_t off = ((size_t)h * SZ_ + s) * HD_ + d;
    *(unsigned*)(qh + off) = (unsigned)f2bf(q0) | ((unsigned)f2bf(q1) << 16);
    *(unsigned*)(kh + off) = (unsigned)f2bf(k0) | ((unsigned)f2bf(k1) << 16);
    *(unsigned*)(vh + off) = (unsigned)f2bf(vv.x) | ((unsigned)f2bf(vv.y) << 16);
}

// ---------------- kernel 4b: V transpose per head: vh[h][s][d] -> vt[h][d][s] ----------------
__global__ __launch_bounds__(256) void vtrans_kernel(
    const unsigned short* __restrict__ vh, unsigned short* __restrict__ vt)
{
    __shared__ __align__(16) unsigned short T[64][72];   // [s][d], padded
    int h = blockIdx.z, d0 = blockIdx.y * 64, s0 = blockIdx.x * 64;
    int t = threadIdx.x;
    int r = t >> 2, c = (t & 3) * 16;
    const unsigned short* src = vh + ((size_t)h * SZ_ + s0 + r) * HD_ + d0 + c;
    *(short8*)&T[r][c]     = *(const short8*)(src);
    *(short8*)&T[r][c + 8] = *(const short8*)(src + 8);
    __syncthreads();
    unsigned short o16[16];
#pragma unroll
    for (int i = 0; i < 16; ++i) o16[i] = T[c + i][r];
    unsigned short* dst = vt + ((size_t)h * HD_ + d0 + r) * SZ_ + s0 + c;
    *(short8*)dst       = *(short8*)&o16[0];
    *(short8*)(dst + 8) = *(short8*)&o16[8];
}

// ---------------- kernel 5: bf16 MFMA flash attention ----------------
// Per wave: 32 queries, KVBLK=64. S^T = mfma(K, Q) so softmax is lane-local (col=q).
// P frags via cvt_pk + permlane32_swap. O^T = mfma(V^T, P). LDS XOR-swizzled.
__global__ __launch_bounds__(256) void attn_mfma_kernel(
    const unsigned short* __restrict__ qh, const unsigned short* __restrict__ kh,
    const unsigned short* __restrict__ vt, float* __restrict__ z)
{
    __shared__ __align__(16) short Ks[64 * 128];   // [key][d], 256B rows, slot^=(key&7)
    __shared__ __align__(16) short Vs[128 * 64];   // [d][key], 128B rows, slot^=(d&7)
    int h = blockIdx.y;
    int t = threadIdx.x;
    int wave = t >> 6, lane = t & 63;
    int l31 = lane & 31, g = lane >> 5;
    int bq = blockIdx.x * 128 + wave * 32;
    const unsigned short* kbase = kh + (size_t)h * SZ_ * HD_;
    const unsigned short* vbase = vt + (size_t)h * HD_ * SZ_;

    // Q B-frags (held in regs): slice s covers head dims [16s,16s+16)
    short8 qf[8];
    {
        const unsigned short* qb = qh + ((size_t)h * SZ_ + bq + l31) * HD_ + g * 8;
#pragma unroll
        for (int s = 0; s < 8; ++s) qf[s] = *(const short8*)(qb + s * 16);
    }

    f32x16 o[4];
#pragma unroll
    for (int db = 0; db < 4; ++db)
#pragma unroll
        for (int r = 0; r < 16; ++r) o[db][r] = 0.f;
    float mreg = -INFINITY, lreg = 0.f;
    bool qY = (bq >= SX_);
    int sw7 = l31 & 7;

    for (int t0 = 0; t0 < SZ_; t0 += 64) {
        __syncthreads();
        {   // stage K tile: 64 rows x 256B
            int r = t >> 2, c = t & 3;
            const unsigned short* src = kbase + (size_t)(t0 + r) * HD_ + c * 32;
            short* dst = Ks + r * 128;
            int r7 = r & 7;
#pragma unroll
            for (int j = 0; j < 4; ++j) {
                short8 v = *(const short8*)(src + j * 8);
                int slot = c * 4 + j;
                int sl = (slot & 8) | ((slot ^ r7) & 7);
                *(short8*)(dst + sl * 8) = v;
            }
            // stage V^T tile: 128 rows x 128B
            int r2 = t >> 1, c2 = t & 1;
            const unsigned short* src2 = vbase + (size_t)r2 * SZ_ + t0 + c2 * 32;
            short* dst2 = Vs + r2 * 64;
            int r27 = r2 & 7;
#pragma unroll
            for (int j = 0; j < 4; ++j) {
                short8 v = *(const short8*)(src2 + j * 8);
                int sl = (c2 * 4 + j) ^ r27;
                *(short8*)(dst2 + sl * 8) = v;
            }
        }
        __syncthreads();

        bool same = (qY == (t0 >= SX_));
        f32x16 sc0, sc1;
#pragma unroll
        for (int r = 0; r < 16; ++r) { sc0[r] = 0.f; sc1[r] = 0.f; }
        const short* Krow0 = Ks + l31 * 128;
        const short* Krow1 = Ks + (l31 + 32) * 128;
#pragma unroll
        for (int s = 4; s < 8; ++s) {       // nope dims always
            int slot = 2 * s + g;
            int sl = (slot & 8) | ((slot ^ sw7) & 7);
            sc0 = __builtin_amdgcn_mfma_f32_32x32x16_bf16(*(const short8*)(Krow0 + sl * 8), qf[s], sc0, 0, 0, 0);
            sc1 = __builtin_amdgcn_mfma_f32_32x32x16_bf16(*(const short8*)(Krow1 + sl * 8), qf[s], sc1, 0, 0, 0);
        }
        if (same) {
#pragma unroll
            for (int s = 0; s < 4; ++s) {   // rope dims only for same-modality
                int slot = 2 * s + g;
                int sl = (slot & 8) | ((slot ^ sw7) & 7);
                sc0 = __builtin_amdgcn_mfma_f32_32x32x16_bf16(*(const short8*)(Krow0 + sl * 8), qf[s], sc0, 0, 0, 0);
                sc1 = __builtin_amdgcn_mfma_f32_32x32x16_bf16(*(const short8*)(Krow1 + sl * 8), qf[s], sc1, 0, 0, 0);
            }
        }

        // online softmax (per-lane q = l31; combine with partner half via xor 32)
        float pm = -INFINITY;
#pragma unroll
        for (int r = 0; r < 16; ++r) pm = fmaxf(pm, fmaxf(sc0[r], sc1[r]));
        pm = fmaxf(pm, __shfl_xor(pm, 32));
        float mnew = fmaxf(mreg, pm);
        float corr = __expf(mreg - mnew);
        mreg = mnew;
        float pp0[16], pp1[16]; float rs = 0.f;
#pragma unroll
        for (int r = 0; r < 16; ++r) {
            pp0[r] = __expf(sc0[r] - mnew);
            pp1[r] = __expf(sc1[r] - mnew);
            rs += pp0[r] + pp1[r];
        }
        rs += __shfl_xor(rs, 32);
        lreg = lreg * corr + rs;
#pragma unroll
        for (int db = 0; db < 4; ++db)
#pragma unroll
            for (int r = 0; r < 16; ++r) o[db][r] *= corr;

        short8 pa0 = mkfrag(&pp0[0]), pa1 = mkfrag(&pp0[8]);
        short8 pa2 = mkfrag(&pp1[0]), pa3 = mkfrag(&pp1[8]);
#pragma unroll
        for (int ks = 0; ks < 4; ++ks) {
            short8 pf = (ks == 0) ? pa0 : (ks == 1) ? pa1 : (ks == 2) ? pa2 : pa3;
#pragma unroll
            for (int db = 0; db < 4; ++db) {
                int row = db * 32 + l31;
                int sl = (2 * ks + g) ^ (l31 & 7);
                const short8 vf = *(const short8*)(Vs + row * 64 + sl * 8);
                o[db] = __builtin_amdgcn_mfma_f32_32x32x16_bf16(vf, pf, o[db], 0, 0, 0);
            }
        }
    }

    float invl = 1.f / lreg;
    float* zp = z + (size_t)(bq + l31) * D_ + h * HD_;
#pragma unroll
    for (int db = 0; db < 4; ++db)
#pragma unroll
        for (int r = 0; r < 16; ++r) {
            int d = db * 32 + (r & 3) + 8 * (r >> 2) + 4 * g;
            zp[d] = o[db][r] * invl;
        }
}

extern "C" void kernel_launch(void* const* d_in, const int* in_sizes, int n_in,
                              void* d_out, int out_size, void* d_ws, size_t ws_size,
                              hipStream_t stream) {
    const float* x    = (const float*)d_in[0];
    const float* y    = (const float*)d_in[1];
    const float* mod  = (const float*)d_in[2];
    const float* fx   = (const float*)d_in[3];
    const float* fy   = (const float*)d_in[4];
    const float* Wqx  = (const float*)d_in[7];
    const float* bqx  = (const float*)d_in[8];
    const float* Wqy  = (const float*)d_in[9];
    const float* bqy  = (const float*)d_in[10];
    const float* Wout = (const float*)d_in[11];
    const float* bout = (const float*)d_in[12];
    const float* wq   = (const float*)d_in[13];
    const float* wk   = (const float*)d_in[14];
    const float* Wmq  = (const float*)d_in[15];
    const float* bmq  = (const float*)d_in[16];
    const float* Wmk  = (const float*)d_in[17];
    const float* bmk  = (const float*)d_in[18];

    float* ws   = (float*)d_ws;
    float* mq   = ws;
    float* mkv  = mq  + NQKV_;
    float* xm   = mkv + NQKV_;
    float* qkv  = xm  + (size_t)SZ_ * D_;
    unsigned short* qh = (unsigned short*)(qkv + (size_t)SZ_ * NQKV_);
    unsigned short* kh = qh + (size_t)H_ * SZ_ * HD_;
    unsigned short* vh = kh + (size_t)H_ * SZ_ * HD_;
    unsigned short* vt = vh + (size_t)H_ * SZ_ * HD_;
    float* z    = xm;                       // alias: xm dead after QKV GEMM
    float* out  = (float*)d_out;

    hipLaunchKernelGGL(mod_gemv_kernel, dim3(2 * NQKV_ / 4), dim3(256), 0, stream,
                       mod, Wmq, bmq, Wmk, bmk, mq, mkv);
    hipLaunchKernelGGL(ln_mod_kernel, dim3(SZ_), dim3(256), 0, stream,
                       x, y, mq, mkv, xm);
    hipLaunchKernelGGL(gemm_kernel, dim3(NQKV_ / 64, SZ_ / 64), dim3(256), 0, stream,
                       xm, Wqx, bqx, Wqy, bqy, qkv, NQKV_,
                       (const float*)nullptr, (const float*)nullptr,
                       (const float*)nullptr, (const float*)nullptr, 0);
    hipLaunchKernelGGL(qkv_transform_kernel, dim3(SZ_ * H_ / 4), dim3(256), 0, stream,
                       qkv, fx, fy, wq, wk, qh, kh, vh);
    hipLaunchKernelGGL(vtrans_kernel, dim3(SZ_ / 64, HD_ / 64, H_), dim3(256), 0, stream,
                       vh, vt);
    hipLaunchKernelGGL(attn_mfma_kernel, dim3(SZ_ / 128, H_), dim3(256), 0, stream,
                       qh, kh, vt, z);
    hipLaunchKernelGGL(gemm_kernel, dim3(D_ / 64, SZ_ / 64), dim3(256), 0, stream,
                       z, Wout, bout, Wout, bout, out, D_,
                       mq + 2 * D_, mkv + 2 * D_, x, y, 1);
}

// Round 4
// 446.062 us; speedup vs baseline: 5.7697x; 3.2275x over previous
//
#include <hip/hip_runtime.h>
#include <math.h>

// Problem constants (B=1)
#define H_    16
#define DR_   64
#define HD_   128
#define D_    2048
#define SX_   2048
#define SY_   512
#define SZ_   2560
#define NQKV_ 6144          // 3*H*HD
#define EPS_  1e-6f
#define ATTN_SCALE 0.07216878364870323f   // 1/sqrt(2*DR+DN) = 1/sqrt(192)

typedef __attribute__((ext_vector_type(8)))  short short8;   // bf16x8 MFMA frag (4 VGPR)
typedef __attribute__((ext_vector_type(16))) float f32x16;   // 32x32 MFMA accum

__device__ __forceinline__ unsigned short f2bf(float f) {
    unsigned u = __builtin_bit_cast(unsigned, f);
    u += 0x7FFF + ((u >> 16) & 1);          // RNE
    return (unsigned short)(u >> 16);
}
__device__ __forceinline__ unsigned pack2(float a, float b) {
    return (unsigned)f2bf(a) | ((unsigned)f2bf(b) << 16);
}
__device__ __forceinline__ float bf2f_lo(unsigned u) {
    return __builtin_bit_cast(float, u << 16);
}
__device__ __forceinline__ float bf2f_hi(unsigned u) {
    return __builtin_bit_cast(float, u & 0xffff0000u);
}

__device__ __forceinline__ unsigned cvtpk_bf16(float lo, float hi) {
    unsigned r;
    asm volatile("v_cvt_pk_bf16_f32 %0, %1, %2" : "=v"(r) : "v"(lo), "v"(hi));
    return r;
}

// async global->LDS, 16B per lane (dest = wave-uniform base + lane*16)
__device__ __forceinline__ void gload16(const unsigned short* g, unsigned short* l) {
    __builtin_amdgcn_global_load_lds(
        (const __attribute__((address_space(1))) unsigned*)g,
        (__attribute__((address_space(3))) unsigned*)l, 16, 0, 0);
}

// Build PV A/B fragment (16 keys) from 8 per-lane P values (C-reg order) via permlane32_swap.
__device__ __forceinline__ short8 mkfrag(const float* p) {
    unsigned a01 = cvtpk_bf16(p[0], p[1]);
    unsigned a23 = cvtpk_bf16(p[2], p[3]);
    unsigned a45 = cvtpk_bf16(p[4], p[5]);
    unsigned a67 = cvtpk_bf16(p[6], p[7]);
    asm volatile("v_permlane32_swap_b32 %0, %1" : "+v"(a01), "+v"(a45));
    asm volatile("v_permlane32_swap_b32 %0, %1" : "+v"(a23), "+v"(a67));
    union { unsigned u[4]; short8 s; } r;
    r.u[0] = a01; r.u[1] = a23; r.u[2] = a45; r.u[3] = a67;
    return r.s;
}

// ---------------- kernel 0: f32 -> bf16 weight conversion ----------------
__global__ __launch_bounds__(256) void cvt_bf16_kernel(
    const float* __restrict__ src, unsigned short* __restrict__ dst, int n)
{
    int i = (blockIdx.x * 256 + threadIdx.x) * 8;
    if (i >= n) return;
    float4 a = *(const float4*)(src + i);
    float4 b = *(const float4*)(src + i + 4);
    uint4 pk;
    pk.x = pack2(a.x, a.y); pk.y = pack2(a.z, a.w);
    pk.z = pack2(b.x, b.y); pk.w = pack2(b.z, b.w);
    *(uint4*)(dst + i) = pk;
}

// ---------------- kernel 1: modulation GEMV ----------------
__global__ __launch_bounds__(256) void mod_gemv_kernel(
    const float* __restrict__ mod,
    const float* __restrict__ Wq, const float* __restrict__ bq,
    const float* __restrict__ Wkv, const float* __restrict__ bkv,
    float* __restrict__ mq, float* __restrict__ mkv)
{
    int t = threadIdx.x;
    int row = blockIdx.x * 4 + (t >> 6);
    int lane = t & 63;
    const float* W; const float* b; float* out; int r;
    if (row < NQKV_) { W = Wq;  b = bq;  out = mq;  r = row; }
    else             { W = Wkv; b = bkv; out = mkv; r = row - NQKV_; }
    const float* wr = W + (size_t)r * D_;
    float s = 0.f;
    for (int k = lane; k < D_; k += 64) s += wr[k] * mod[k];
#pragma unroll
    for (int m = 32; m >= 1; m >>= 1) s += __shfl_xor(s, m);
    if (lane == 0) out[r] = s + b[r];
}

// ---------------- kernel 2: LayerNorm + modulation, bf16 out ----------------
__global__ __launch_bounds__(256) void ln_mod_kernel(
    const float* __restrict__ x, const float* __restrict__ y,
    const float* __restrict__ mq, const float* __restrict__ mkv,
    unsigned short* __restrict__ xm)
{
    __shared__ float red[8];
    int s = blockIdx.x, t = threadIdx.x;
    const float* src; const float* mv;
    if (s < SX_) { src = x + (size_t)s * D_;          mv = mq; }
    else         { src = y + (size_t)(s - SX_) * D_;  mv = mkv; }
    float a[8];
    *(float4*)&a[0] = *(const float4*)(src + t * 8);
    *(float4*)&a[4] = *(const float4*)(src + t * 8 + 4);
    float sum = 0.f, ssq = 0.f;
#pragma unroll
    for (int i = 0; i < 8; ++i) { sum += a[i]; ssq += a[i] * a[i]; }
#pragma unroll
    for (int m = 32; m >= 1; m >>= 1) { sum += __shfl_xor(sum, m); ssq += __shfl_xor(ssq, m); }
    if ((t & 63) == 0) { red[t >> 6] = sum; red[4 + (t >> 6)] = ssq; }
    __syncthreads();
    float tot  = red[0] + red[1] + red[2] + red[3];
    float totq = red[4] + red[5] + red[6] + red[7];
    float mean = tot * (1.f / (float)D_);
    float var  = totq * (1.f / (float)D_) - mean * mean;
    float inv  = rsqrtf(var + EPS_);
    float o[8];
#pragma unroll
    for (int i = 0; i < 8; ++i) {
        int c = t * 8 + i;
        float v = (a[i] - mean) * inv;
        o[i] = (1.f + mv[D_ + c]) * v + mv[c];
    }
    uint4 pk;
    pk.x = pack2(o[0], o[1]); pk.y = pack2(o[2], o[3]);
    pk.z = pack2(o[4], o[5]); pk.w = pack2(o[6], o[7]);
    *(uint4*)(xm + (size_t)s * D_ + t * 8) = pk;
}

// ---------------- kernel 3: bf16 MFMA GEMM  C = A @ W^T + b ----------------
// A: (M,2048) bf16 row-major. W: (N,2048) bf16 row-major (rows<SX_: Wx, else Wy).
// 128x128 tile, BK=32, 4 waves (2x2), wave tile 64x64 = 2x2 mfma_32x32x16.
// global_load_lds staging with pre-swizzled source (slot ^= row&3); reads use same XOR.
// mode 0: store bf16. mode 1: store f32 with gate+residual epilogue.
__global__ __launch_bounds__(256) void gemm_bf16_kernel(
    const unsigned short* __restrict__ A,
    const unsigned short* __restrict__ Wx, const float* __restrict__ bx,
    const unsigned short* __restrict__ Wy, const float* __restrict__ by,
    void* __restrict__ Cout, int N,
    const float* __restrict__ gx, const float* __restrict__ gy,
    const float* __restrict__ rx, const float* __restrict__ ry,
    int mode)
{
    __shared__ __align__(16) unsigned short As[128 * 32];
    __shared__ __align__(16) unsigned short Bs[128 * 32];
    int m0 = blockIdx.y * 128, n0 = blockIdx.x * 128;
    const unsigned short* W = (m0 < SX_) ? Wx : Wy;
    const float* bb = (m0 < SX_) ? bx : by;
    int t = threadIdx.x;
    int wv = t >> 6, lane = t & 63, l31 = lane & 31, g = lane >> 5;
    int wr = wv >> 1, wc = wv & 1;
    int srow = t >> 2, ssl = t & 3;
    const unsigned short* gA = A + (size_t)(m0 + srow) * D_ + ((ssl ^ (srow & 3)) * 8);
    const unsigned short* gW = W + (size_t)(n0 + srow) * D_ + ((ssl ^ (srow & 3)) * 8);
    f32x16 acc[2][2];
#pragma unroll
    for (int i = 0; i < 2; ++i)
#pragma unroll
        for (int j = 0; j < 2; ++j)
#pragma unroll
            for (int r = 0; r < 16; ++r) acc[i][j][r] = 0.f;
    int arow = wr * 64 + l31;       // + i*32 : rows of A (B-operand)
    int wrow = wc * 64 + l31;       // + j*32 : rows of W (A-operand)
    int a3 = arow & 3, w3 = wrow & 3;   // (i*32 doesn't change &3)

    for (int k0 = 0; k0 < D_; k0 += 32) {
        __syncthreads();
        gload16(gA + k0,            &As[wv * 512]);
        gload16(gA + 64 * D_ + k0,  &As[2048 + wv * 512]);
        gload16(gW + k0,            &Bs[wv * 512]);
        gload16(gW + 64 * D_ + k0,  &Bs[2048 + wv * 512]);
        __syncthreads();
#pragma unroll
        for (int kk = 0; kk < 2; ++kk) {
            int slot = kk * 2 + g;
            short8 af[2], wf[2];
#pragma unroll
            for (int i = 0; i < 2; ++i) {
                af[i] = *(const short8*)&As[(arow + i * 32) * 32 + ((slot ^ a3) * 8)];
                wf[i] = *(const short8*)&Bs[(wrow + i * 32) * 32 + ((slot ^ w3) * 8)];
            }
#pragma unroll
            for (int i = 0; i < 2; ++i)
#pragma unroll
                for (int j = 0; j < 2; ++j)
                    acc[i][j] = __builtin_amdgcn_mfma_f32_32x32x16_bf16(wf[j], af[i], acc[i][j], 0, 0, 0);
        }
    }

#pragma unroll
    for (int i = 0; i < 2; ++i) {
        int row = m0 + wr * 64 + i * 32 + l31;
        if (mode == 0) {
            unsigned short* C = (unsigned short*)Cout;
#pragma unroll
            for (int j = 0; j < 2; ++j)
#pragma unroll
                for (int q = 0; q < 4; ++q) {
                    int n = n0 + wc * 64 + j * 32 + q * 8 + 4 * g;
                    float o0 = acc[i][j][q * 4 + 0] + bb[n + 0];
                    float o1 = acc[i][j][q * 4 + 1] + bb[n + 1];
                    float o2 = acc[i][j][q * 4 + 2] + bb[n + 2];
                    float o3 = acc[i][j][q * 4 + 3] + bb[n + 3];
                    *(uint2*)(C + (size_t)row * N + n) = make_uint2(pack2(o0, o1), pack2(o2, o3));
                }
        } else {
            float* C = (float*)Cout;
            const float* gt = (row < SX_) ? gx : gy;
            const float* rr = (row < SX_) ? rx + (size_t)row * N : ry + (size_t)(row - SX_) * N;
#pragma unroll
            for (int j = 0; j < 2; ++j)
#pragma unroll
                for (int q = 0; q < 4; ++q) {
                    int n = n0 + wc * 64 + j * 32 + q * 8 + 4 * g;
                    float4 o;
                    o.x = (acc[i][j][q * 4 + 0] + bb[n + 0]) * gt[n + 0] + rr[n + 0];
                    o.y = (acc[i][j][q * 4 + 1] + bb[n + 1]) * gt[n + 1] + rr[n + 1];
                    o.z = (acc[i][j][q * 4 + 2] + bb[n + 2]) * gt[n + 2] + rr[n + 2];
                    o.w = (acc[i][j][q * 4 + 3] + bb[n + 3]) * gt[n + 3] + rr[n + 3];
                    *(float4*)(C + (size_t)row * N + n) = o;
                }
        }
    }
}

// ---------------- kernel 4: RMS + RoPE + head-major transpose (bf16 in/out) ----------------
__global__ __launch_bounds__(256) void qkv_transform_kernel(
    const unsigned short* __restrict__ qkv,
    const float* __restrict__ fx, const float* __restrict__ fy,
    const float* __restrict__ wq, const float* __restrict__ wk,
    unsigned short* __restrict__ qh, unsigned short* __restrict__ kh,
    unsigned short* __restrict__ vh)
{
    int t = threadIdx.x;
    int gid = blockIdx.x * 4 + (t >> 6);
    int lane = t & 63;
    int s = gid >> 4;
    int h = gid & 15;
    const unsigned short* base = qkv + (size_t)s * NQKV_ + h * HD_;
    int d = lane * 2;
    unsigned qu = *(const unsigned*)(base + d);
    unsigned ku = *(const unsigned*)(base + 2048 + d);
    unsigned vu = *(const unsigned*)(base + 4096 + d);
    float qx = bf2f_lo(qu), qy = bf2f_hi(qu);
    float kx = bf2f_lo(ku), ky = bf2f_hi(ku);
    float sq = qx * qx + qy * qy;
    float sk = kx * kx + ky * ky;
#pragma unroll
    for (int m = 32; m >= 1; m >>= 1) { sq += __shfl_xor(sq, m); sk += __shfl_xor(sk, m); }
    float qs = rsqrtf(sq * (1.f / 128.f) + EPS_) * ATTN_SCALE;
    float ks = rsqrtf(sk * (1.f / 128.f) + EPS_);
    float q0 = qx * qs * wq[d], q1 = qy * qs * wq[d + 1];
    float k0 = kx * ks * wk[d], k1 = ky * ks * wk[d + 1];
    if (lane < 32) {
        const float* f = (s < SX_) ? fx + (size_t)s * DR_ + d
                                   : fy + (size_t)(s - SX_) * DR_ + d;
        float cs = f[0], sn = f[1];
        float o0 = q0 * cs - q1 * sn, o1 = q0 * sn + q1 * cs;
        q0 = o0; q1 = o1;
        o0 = k0 * cs - k1 * sn; o1 = k0 * sn + k1 * cs;
        k0 = o0; k1 = o1;
    }
    size_t off = ((size_t)h * SZ_ + s) * HD_ + d;
    *(unsigned*)(qh + off) = pack2(q0, q1);
    *(unsigned*)(kh + off) = pack2(k0, k1);
    *(unsigned*)(vh + off) = vu;
}

// ---------------- kernel 4b: V transpose per head: vh[h][s][d] -> vt[h][d][s] ----------------
__global__ __launch_bounds__(256) void vtrans_kernel(
    const unsigned short* __restrict__ vh, unsigned short* __restrict__ vt)
{
    __shared__ __align__(16) unsigned short T[64][72];
    int h = blockIdx.z, d0 = blockIdx.y * 64, s0 = blockIdx.x * 64;
    int t = threadIdx.x;
    int r = t >> 2, c = (t & 3) * 16;
    const unsigned short* src = vh + ((size_t)h * SZ_ + s0 + r) * HD_ + d0 + c;
    *(short8*)&T[r][c]     = *(const short8*)(src);
    *(short8*)&T[r][c + 8] = *(const short8*)(src + 8);
    __syncthreads();
    unsigned short o16[16];
#pragma unroll
    for (int i = 0; i < 16; ++i) o16[i] = T[c + i][r];
    unsigned short* dst = vt + ((size_t)h * HD_ + d0 + r) * SZ_ + s0 + c;
    *(short8*)dst       = *(short8*)&o16[0];
    *(short8*)(dst + 8) = *(short8*)&o16[8];
}

// ---------------- kernel 5: bf16 MFMA flash attention (z out bf16) ----------------
__global__ __launch_bounds__(256) void attn_mfma_kernel(
    const unsigned short* __restrict__ qh, const unsigned short* __restrict__ kh,
    const unsigned short* __restrict__ vt, unsigned short* __restrict__ z)
{
    __shared__ __align__(16) short Ks[64 * 128];   // [key][d], 256B rows, slot^=(key&7)
    __shared__ __align__(16) short Vs[128 * 64];   // [d][key], 128B rows, slot^=(d&7)
    int h = blockIdx.y;
    int t = threadIdx.x;
    int wave = t >> 6, lane = t & 63;
    int l31 = lane & 31, g = lane >> 5;
    int bq = blockIdx.x * 128 + wave * 32;
    const unsigned short* kbase = kh + (size_t)h * SZ_ * HD_;
    const unsigned short* vbase = vt + (size_t)h * HD_ * SZ_;

    short8 qf[8];
    {
        const unsigned short* qb = qh + ((size_t)h * SZ_ + bq + l31) * HD_ + g * 8;
#pragma unroll
        for (int s = 0; s < 8; ++s) qf[s] = *(const short8*)(qb + s * 16);
    }

    f32x16 o[4];
#pragma unroll
    for (int db = 0; db < 4; ++db)
#pragma unroll
        for (int r = 0; r < 16; ++r) o[db][r] = 0.f;
    float mreg = -INFINITY, lreg = 0.f;
    bool qY = (bq >= SX_);
    int sw7 = l31 & 7;

    for (int t0 = 0; t0 < SZ_; t0 += 64) {
        __syncthreads();
        {
            int r = t >> 2, c = t & 3;
            const unsigned short* src = kbase + (size_t)(t0 + r) * HD_ + c * 32;
            short* dst = Ks + r * 128;
            int r7 = r & 7;
#pragma unroll
            for (int j = 0; j < 4; ++j) {
                short8 v = *(const short8*)(src + j * 8);
                int slot = c * 4 + j;
                int sl = (slot & 8) | ((slot ^ r7) & 7);
                *(short8*)(dst + sl * 8) = v;
            }
            int r2 = t >> 1, c2 = t & 1;
            const unsigned short* src2 = vbase + (size_t)r2 * SZ_ + t0 + c2 * 32;
            short* dst2 = Vs + r2 * 64;
            int r27 = r2 & 7;
#pragma unroll
            for (int j = 0; j < 4; ++j) {
                short8 v = *(const short8*)(src2 + j * 8);
                int sl = (c2 * 4 + j) ^ r27;
                *(short8*)(dst2 + sl * 8) = v;
            }
        }
        __syncthreads();

        bool same = (qY == (t0 >= SX_));
        f32x16 sc0, sc1;
#pragma unroll
        for (int r = 0; r < 16; ++r) { sc0[r] = 0.f; sc1[r] = 0.f; }
        const short* Krow0 = Ks + l31 * 128;
        const short* Krow1 = Ks + (l31 + 32) * 128;
#pragma unroll
        for (int s = 4; s < 8; ++s) {
            int slot = 2 * s + g;
            int sl = (slot & 8) | ((slot ^ sw7) & 7);
            sc0 = __builtin_amdgcn_mfma_f32_32x32x16_bf16(*(const short8*)(Krow0 + sl * 8), qf[s], sc0, 0, 0, 0);
            sc1 = __builtin_amdgcn_mfma_f32_32x32x16_bf16(*(const short8*)(Krow1 + sl * 8), qf[s], sc1, 0, 0, 0);
        }
        if (same) {
#pragma unroll
            for (int s = 0; s < 4; ++s) {
                int slot = 2 * s + g;
                int sl = (slot & 8) | ((slot ^ sw7) & 7);
                sc0 = __builtin_amdgcn_mfma_f32_32x32x16_bf16(*(const short8*)(Krow0 + sl * 8), qf[s], sc0, 0, 0, 0);
                sc1 = __builtin_amdgcn_mfma_f32_32x32x16_bf16(*(const short8*)(Krow1 + sl * 8), qf[s], sc1, 0, 0, 0);
            }
        }

        float pm = -INFINITY;
#pragma unroll
        for (int r = 0; r < 16; ++r) pm = fmaxf(pm, fmaxf(sc0[r], sc1[r]));
        pm = fmaxf(pm, __shfl_xor(pm, 32));
        float mnew = fmaxf(mreg, pm);
        float corr = __expf(mreg - mnew);
        mreg = mnew;
        float pp0[16], pp1[16]; float rs = 0.f;
#pragma unroll
        for (int r = 0; r < 16; ++r) {
            pp0[r] = __expf(sc0[r] - mnew);
            pp1[r] = __expf(sc1[r] - mnew);
            rs += pp0[r] + pp1[r];
        }
        rs += __shfl_xor(rs, 32);
        lreg = lreg * corr + rs;
#pragma unroll
        for (int db = 0; db < 4; ++db)
#pragma unroll
            for (int r = 0; r < 16; ++r) o[db][r] *= corr;

        short8 pa0 = mkfrag(&pp0[0]), pa1 = mkfrag(&pp0[8]);
        short8 pa2 = mkfrag(&pp1[0]), pa3 = mkfrag(&pp1[8]);
#pragma unroll
        for (int ks = 0; ks < 4; ++ks) {
            short8 pf = (ks == 0) ? pa0 : (ks == 1) ? pa1 : (ks == 2) ? pa2 : pa3;
#pragma unroll
            for (int db = 0; db < 4; ++db) {
                int row = db * 32 + l31;
                int sl = (2 * ks + g) ^ (l31 & 7);
                const short8 vf = *(const short8*)(Vs + row * 64 + sl * 8);
                o[db] = __builtin_amdgcn_mfma_f32_32x32x16_bf16(vf, pf, o[db], 0, 0, 0);
            }
        }
    }

    float invl = 1.f / lreg;
    unsigned short* zp = z + (size_t)(bq + l31) * D_ + h * HD_;
#pragma unroll
    for (int db = 0; db < 4; ++db)
#pragma unroll
        for (int r = 0; r < 16; ++r) {
            int d = db * 32 + (r & 3) + 8 * (r >> 2) + 4 * g;
            zp[d] = f2bf(o[db][r] * invl);
        }
}

extern "C" void kernel_launch(void* const* d_in, const int* in_sizes, int n_in,
                              void* d_out, int out_size, void* d_ws, size_t ws_size,
                              hipStream_t stream) {
    const float* x    = (const float*)d_in[0];
    const float* y    = (const float*)d_in[1];
    const float* mod  = (const float*)d_in[2];
    const float* fx   = (const float*)d_in[3];
    const float* fy   = (const float*)d_in[4];
    const float* Wqx  = (const float*)d_in[7];
    const float* bqx  = (const float*)d_in[8];
    const float* Wqy  = (const float*)d_in[9];
    const float* bqy  = (const float*)d_in[10];
    const float* Wout = (const float*)d_in[11];
    const float* bout = (const float*)d_in[12];
    const float* wq   = (const float*)d_in[13];
    const float* wk   = (const float*)d_in[14];
    const float* Wmq  = (const float*)d_in[15];
    const float* bmq  = (const float*)d_in[16];
    const float* Wmk  = (const float*)d_in[17];
    const float* bmk  = (const float*)d_in[18];

    // workspace layout — total ≈ 142.8 MB (proven-working bound: 147 MB)
    float* mq   = (float*)d_ws;                              // 6144
    float* mkv  = mq + NQKV_;                                // 6144
    unsigned short* xm   = (unsigned short*)(mkv + NQKV_);   // SZ*D bf16 (later: z)
    unsigned short* qkvb = xm + (size_t)SZ_ * D_;            // SZ*6144 bf16
    unsigned short* qh   = qkvb + (size_t)SZ_ * NQKV_;       // H*SZ*HD bf16 each
    unsigned short* kh   = qh + (size_t)H_ * SZ_ * HD_;
    unsigned short* vh   = kh + (size_t)H_ * SZ_ * HD_;
    unsigned short* vt   = vh + (size_t)H_ * SZ_ * HD_;
    unsigned short* wqxb = vt + (size_t)H_ * SZ_ * HD_;      // 6144*2048 bf16
    unsigned short* wqyb = wqxb + (size_t)NQKV_ * D_;
    unsigned short* wob  = wqyb + (size_t)NQKV_ * D_;        // 2048*2048 bf16
    unsigned short* z    = xm;                               // alias: xm dead after QKV GEMM
    float* out  = (float*)d_out;

    hipLaunchKernelGGL(cvt_bf16_kernel, dim3(NQKV_ * D_ / 2048), dim3(256), 0, stream,
                       Wqx, wqxb, NQKV_ * D_);
    hipLaunchKernelGGL(cvt_bf16_kernel, dim3(NQKV_ * D_ / 2048), dim3(256), 0, stream,
                       Wqy, wqyb, NQKV_ * D_);
    hipLaunchKernelGGL(cvt_bf16_kernel, dim3(D_ * D_ / 2048), dim3(256), 0, stream,
                       Wout, wob, D_ * D_);
    hipLaunchKernelGGL(mod_gemv_kernel, dim3(2 * NQKV_ / 4), dim3(256), 0, stream,
                       mod, Wmq, bmq, Wmk, bmk, mq, mkv);
    hipLaunchKernelGGL(ln_mod_kernel, dim3(SZ_), dim3(256), 0, stream,
                       x, y, mq, mkv, xm);
    hipLaunchKernelGGL(gemm_bf16_kernel, dim3(NQKV_ / 128, SZ_ / 128), dim3(256), 0, stream,
                       xm, wqxb, bqx, wqyb, bqy, (void*)qkvb, NQKV_,
                       (const float*)nullptr, (const float*)nullptr,
                       (const float*)nullptr, (const float*)nullptr, 0);
    hipLaunchKernelGGL(qkv_transform_kernel, dim3(SZ_ * H_ / 4), dim3(256), 0, stream,
                       qkvb, fx, fy, wq, wk, qh, kh, vh);
    hipLaunchKernelGGL(vtrans_kernel, dim3(SZ_ / 64, HD_ / 64, H_), dim3(256), 0, stream,
                       vh, vt);
    hipLaunchKernelGGL(attn_mfma_kernel, dim3(SZ_ / 128, H_), dim3(256), 0, stream,
                       qh, kh, vt, z);
    hipLaunchKernelGGL(gemm_bf16_kernel, dim3(D_ / 128, SZ_ / 128), dim3(256), 0, stream,
                       z, wob, bout, wob, bout, (void*)out, D_,
                       mq + 2 * D_, mkv + 2 * D_, x, y, 1);
}

// Round 6
// 395.965 us; speedup vs baseline: 6.4996x; 1.1265x over previous
//
#include <hip/hip_runtime.h>
#include <math.h>

// Problem constants (B=1)
#define H_    16
#define DR_   64
#define HD_   128
#define D_    2048
#define SX_   2048
#define SY_   512
#define SZ_   2560
#define NQKV_ 6144          // 3*H*HD
#define EPS_  1e-6f
#define ATTN_SCALE 0.07216878364870323f   // 1/sqrt(2*DR+DN) = 1/sqrt(192)
#define NS_   4             // KV splits (flash-decode)
#define SPL_  (SZ_ / NS_)   // 640 keys per split (multiple of 64)
#define QT_   (SZ_ / 128)   // 20 q-tiles

typedef __attribute__((ext_vector_type(8)))  short short8;   // bf16x8 MFMA frag (4 VGPR)
typedef __attribute__((ext_vector_type(16))) float f32x16;   // 32x32 MFMA accum

__device__ __forceinline__ unsigned short f2bf(float f) {
    unsigned u = __builtin_bit_cast(unsigned, f);
    u += 0x7FFF + ((u >> 16) & 1);          // RNE
    return (unsigned short)(u >> 16);
}
__device__ __forceinline__ unsigned pack2(float a, float b) {
    return (unsigned)f2bf(a) | ((unsigned)f2bf(b) << 16);
}
__device__ __forceinline__ float bf2f_lo(unsigned u) {
    return __builtin_bit_cast(float, u << 16);
}
__device__ __forceinline__ float bf2f_hi(unsigned u) {
    return __builtin_bit_cast(float, u & 0xffff0000u);
}

__device__ __forceinline__ unsigned cvtpk_bf16(float lo, float hi) {
    unsigned r;
    asm volatile("v_cvt_pk_bf16_f32 %0, %1, %2" : "=v"(r) : "v"(lo), "v"(hi));
    return r;
}

// async global->LDS, 16B per lane (dest = wave-uniform base + lane*16)
__device__ __forceinline__ void gload16(const unsigned short* g, unsigned short* l) {
    __builtin_amdgcn_global_load_lds(
        (const __attribute__((address_space(1))) unsigned*)g,
        (__attribute__((address_space(3))) unsigned*)l, 16, 0, 0);
}

// Build PV A/B fragment (16 keys) from 8 per-lane P values (C-reg order) via permlane32_swap.
__device__ __forceinline__ short8 mkfrag(const float* p) {
    unsigned a01 = cvtpk_bf16(p[0], p[1]);
    unsigned a23 = cvtpk_bf16(p[2], p[3]);
    unsigned a45 = cvtpk_bf16(p[4], p[5]);
    unsigned a67 = cvtpk_bf16(p[6], p[7]);
    asm volatile("v_permlane32_swap_b32 %0, %1" : "+v"(a01), "+v"(a45));
    asm volatile("v_permlane32_swap_b32 %0, %1" : "+v"(a23), "+v"(a67));
    union { unsigned u[4]; short8 s; } r;
    r.u[0] = a01; r.u[1] = a23; r.u[2] = a45; r.u[3] = a67;
    return r.s;
}

// ---------------- kernel 0: f32 -> bf16 weight conversion ----------------
__global__ __launch_bounds__(256) void cvt_bf16_kernel(
    const float* __restrict__ src, unsigned short* __restrict__ dst, int n)
{
    int i = (blockIdx.x * 256 + threadIdx.x) * 8;
    if (i >= n) return;
    float4 a = *(const float4*)(src + i);
    float4 b = *(const float4*)(src + i + 4);
    uint4 pk;
    pk.x = pack2(a.x, a.y); pk.y = pack2(a.z, a.w);
    pk.z = pack2(b.x, b.y); pk.w = pack2(b.z, b.w);
    *(uint4*)(dst + i) = pk;
}

// ---------------- kernel 1: modulation GEMV ----------------
__global__ __launch_bounds__(256) void mod_gemv_kernel(
    const float* __restrict__ mod,
    const float* __restrict__ Wq, const float* __restrict__ bq,
    const float* __restrict__ Wkv, const float* __restrict__ bkv,
    float* __restrict__ mq, float* __restrict__ mkv)
{
    int t = threadIdx.x;
    int row = blockIdx.x * 4 + (t >> 6);
    int lane = t & 63;
    const float* W; const float* b; float* out; int r;
    if (row < NQKV_) { W = Wq;  b = bq;  out = mq;  r = row; }
    else             { W = Wkv; b = bkv; out = mkv; r = row - NQKV_; }
    const float* wr = W + (size_t)r * D_;
    float s = 0.f;
    for (int k = lane; k < D_; k += 64) s += wr[k] * mod[k];
#pragma unroll
    for (int m = 32; m >= 1; m >>= 1) s += __shfl_xor(s, m);
    if (lane == 0) out[r] = s + b[r];
}

// ---------------- kernel 2: LayerNorm + modulation, bf16 out ----------------
__global__ __launch_bounds__(256) void ln_mod_kernel(
    const float* __restrict__ x, const float* __restrict__ y,
    const float* __restrict__ mq, const float* __restrict__ mkv,
    unsigned short* __restrict__ xm)
{
    __shared__ float red[8];
    int s = blockIdx.x, t = threadIdx.x;
    const float* src; const float* mv;
    if (s < SX_) { src = x + (size_t)s * D_;          mv = mq; }
    else         { src = y + (size_t)(s - SX_) * D_;  mv = mkv; }
    float a[8];
    *(float4*)&a[0] = *(const float4*)(src + t * 8);
    *(float4*)&a[4] = *(const float4*)(src + t * 8 + 4);
    float sum = 0.f, ssq = 0.f;
#pragma unroll
    for (int i = 0; i < 8; ++i) { sum += a[i]; ssq += a[i] * a[i]; }
#pragma unroll
    for (int m = 32; m >= 1; m >>= 1) { sum += __shfl_xor(sum, m); ssq += __shfl_xor(ssq, m); }
    if ((t & 63) == 0) { red[t >> 6] = sum; red[4 + (t >> 6)] = ssq; }
    __syncthreads();
    float tot  = red[0] + red[1] + red[2] + red[3];
    float totq = red[4] + red[5] + red[6] + red[7];
    float mean = tot * (1.f / (float)D_);
    float var  = totq * (1.f / (float)D_) - mean * mean;
    float inv  = rsqrtf(var + EPS_);
    float o[8];
#pragma unroll
    for (int i = 0; i < 8; ++i) {
        int c = t * 8 + i;
        float v = (a[i] - mean) * inv;
        o[i] = (1.f + mv[D_ + c]) * v + mv[c];
    }
    uint4 pk;
    pk.x = pack2(o[0], o[1]); pk.y = pack2(o[2], o[3]);
    pk.z = pack2(o[4], o[5]); pk.w = pack2(o[6], o[7]);
    *(uint4*)(xm + (size_t)s * D_ + t * 8) = pk;
}

// ---------------- kernel 3: bf16 MFMA GEMM  C = A @ W^T + b ----------------
// 128x128 tile, BK=32, 4 waves (2x2), wave tile 64x64 = 2x2 mfma_32x32x16.
// global_load_lds staging with pre-swizzled source (slot ^= row&3); reads use same XOR.
// mode 0: store bf16. mode 1: store f32 with gate+residual epilogue.
__global__ __launch_bounds__(256) void gemm_bf16_kernel(
    const unsigned short* __restrict__ A,
    const unsigned short* __restrict__ Wx, const float* __restrict__ bx,
    const unsigned short* __restrict__ Wy, const float* __restrict__ by,
    void* __restrict__ Cout, int N,
    const float* __restrict__ gx, const float* __restrict__ gy,
    const float* __restrict__ rx, const float* __restrict__ ry,
    int mode)
{
    __shared__ __align__(16) unsigned short As[128 * 32];
    __shared__ __align__(16) unsigned short Bs[128 * 32];
    int m0 = blockIdx.y * 128, n0 = blockIdx.x * 128;
    const unsigned short* W = (m0 < SX_) ? Wx : Wy;
    const float* bb = (m0 < SX_) ? bx : by;
    int t = threadIdx.x;
    int wv = t >> 6, lane = t & 63, l31 = lane & 31, g = lane >> 5;
    int wr = wv >> 1, wc = wv & 1;
    int srow = t >> 2, ssl = t & 3;
    const unsigned short* gA = A + (size_t)(m0 + srow) * D_ + ((ssl ^ (srow & 3)) * 8);
    const unsigned short* gW = W + (size_t)(n0 + srow) * D_ + ((ssl ^ (srow & 3)) * 8);
    f32x16 acc[2][2];
#pragma unroll
    for (int i = 0; i < 2; ++i)
#pragma unroll
        for (int j = 0; j < 2; ++j)
#pragma unroll
            for (int r = 0; r < 16; ++r) acc[i][j][r] = 0.f;
    int arow = wr * 64 + l31;
    int wrow = wc * 64 + l31;
    int a3 = arow & 3, w3 = wrow & 3;

    for (int k0 = 0; k0 < D_; k0 += 32) {
        __syncthreads();
        gload16(gA + k0,            &As[wv * 512]);
        gload16(gA + 64 * D_ + k0,  &As[2048 + wv * 512]);
        gload16(gW + k0,            &Bs[wv * 512]);
        gload16(gW + 64 * D_ + k0,  &Bs[2048 + wv * 512]);
        __syncthreads();
#pragma unroll
        for (int kk = 0; kk < 2; ++kk) {
            int slot = kk * 2 + g;
            short8 af[2], wf[2];
#pragma unroll
            for (int i = 0; i < 2; ++i) {
                af[i] = *(const short8*)&As[(arow + i * 32) * 32 + ((slot ^ a3) * 8)];
                wf[i] = *(const short8*)&Bs[(wrow + i * 32) * 32 + ((slot ^ w3) * 8)];
            }
#pragma unroll
            for (int i = 0; i < 2; ++i)
#pragma unroll
                for (int j = 0; j < 2; ++j)
                    acc[i][j] = __builtin_amdgcn_mfma_f32_32x32x16_bf16(wf[j], af[i], acc[i][j], 0, 0, 0);
        }
    }

#pragma unroll
    for (int i = 0; i < 2; ++i) {
        int row = m0 + wr * 64 + i * 32 + l31;
        if (mode == 0) {
            unsigned short* C = (unsigned short*)Cout;
#pragma unroll
            for (int j = 0; j < 2; ++j)
#pragma unroll
                for (int q = 0; q < 4; ++q) {
                    int n = n0 + wc * 64 + j * 32 + q * 8 + 4 * g;
                    float o0 = acc[i][j][q * 4 + 0] + bb[n + 0];
                    float o1 = acc[i][j][q * 4 + 1] + bb[n + 1];
                    float o2 = acc[i][j][q * 4 + 2] + bb[n + 2];
                    float o3 = acc[i][j][q * 4 + 3] + bb[n + 3];
                    *(uint2*)(C + (size_t)row * N + n) = make_uint2(pack2(o0, o1), pack2(o2, o3));
                }
        } else {
            float* C = (float*)Cout;
            const float* gt = (row < SX_) ? gx : gy;
            const float* rr = (row < SX_) ? rx + (size_t)row * N : ry + (size_t)(row - SX_) * N;
#pragma unroll
            for (int j = 0; j < 2; ++j)
#pragma unroll
                for (int q = 0; q < 4; ++q) {
                    int n = n0 + wc * 64 + j * 32 + q * 8 + 4 * g;
                    float4 o;
                    o.x = (acc[i][j][q * 4 + 0] + bb[n + 0]) * gt[n + 0] + rr[n + 0];
                    o.y = (acc[i][j][q * 4 + 1] + bb[n + 1]) * gt[n + 1] + rr[n + 1];
                    o.z = (acc[i][j][q * 4 + 2] + bb[n + 2]) * gt[n + 2] + rr[n + 2];
                    o.w = (acc[i][j][q * 4 + 3] + bb[n + 3]) * gt[n + 3] + rr[n + 3];
                    *(float4*)(C + (size_t)row * N + n) = o;
                }
        }
    }
}

// ---------------- kernel 4: RMS + RoPE + head-major transpose (bf16 in/out) ----------------
__global__ __launch_bounds__(256) void qkv_transform_kernel(
    const unsigned short* __restrict__ qkv,
    const float* __restrict__ fx, const float* __restrict__ fy,
    const float* __restrict__ wq, const float* __restrict__ wk,
    unsigned short* __restrict__ qh, unsigned short* __restrict__ kh,
    unsigned short* __restrict__ vh)
{
    int t = threadIdx.x;
    int gid = blockIdx.x * 4 + (t >> 6);
    int lane = t & 63;
    int s = gid >> 4;
    int h = gid & 15;
    const unsigned short* base = qkv + (size_t)s * NQKV_ + h * HD_;
    int d = lane * 2;
    unsigned qu = *(const unsigned*)(base + d);
    unsigned ku = *(const unsigned*)(base + 2048 + d);
    unsigned vu = *(const unsigned*)(base + 4096 + d);
    float qx = bf2f_lo(qu), qy = bf2f_hi(qu);
    float kx = bf2f_lo(ku), ky = bf2f_hi(ku);
    float sq = qx * qx + qy * qy;
    float sk = kx * kx + ky * ky;
#pragma unroll
    for (int m = 32; m >= 1; m >>= 1) { sq += __shfl_xor(sq, m); sk += __shfl_xor(sk, m); }
    float qs = rsqrtf(sq * (1.f / 128.f) + EPS_) * ATTN_SCALE;
    float ks = rsqrtf(sk * (1.f / 128.f) + EPS_);
    float q0 = qx * qs * wq[d], q1 = qy * qs * wq[d + 1];
    float k0 = kx * ks * wk[d], k1 = ky * ks * wk[d + 1];
    if (lane < 32) {
        const float* f = (s < SX_) ? fx + (size_t)s * DR_ + d
                                   : fy + (size_t)(s - SX_) * DR_ + d;
        float cs = f[0], sn = f[1];
        float o0 = q0 * cs - q1 * sn, o1 = q0 * sn + q1 * cs;
        q0 = o0; q1 = o1;
        o0 = k0 * cs - k1 * sn; o1 = k0 * sn + k1 * cs;
        k0 = o0; k1 = o1;
    }
    size_t off = ((size_t)h * SZ_ + s) * HD_ + d;
    *(unsigned*)(qh + off) = pack2(q0, q1);
    *(unsigned*)(kh + off) = pack2(k0, k1);
    *(unsigned*)(vh + off) = vu;
}

// ---------------- kernel 4b: V transpose per head: vh[h][s][d] -> vt[h][d][s] ----------------
__global__ __launch_bounds__(256) void vtrans_kernel(
    const unsigned short* __restrict__ vh, unsigned short* __restrict__ vt)
{
    __shared__ __align__(16) unsigned short T[64][72];
    int h = blockIdx.z, d0 = blockIdx.y * 64, s0 = blockIdx.x * 64;
    int t = threadIdx.x;
    int r = t >> 2, c = (t & 3) * 16;
    const unsigned short* src = vh + ((size_t)h * SZ_ + s0 + r) * HD_ + d0 + c;
    *(short8*)&T[r][c]     = *(const short8*)(src);
    *(short8*)&T[r][c + 8] = *(const short8*)(src + 8);
    __syncthreads();
    unsigned short o16[16];
#pragma unroll
    for (int i = 0; i < 16; ++i) o16[i] = T[c + i][r];
    unsigned short* dst = vt + ((size_t)h * HD_ + d0 + r) * SZ_ + s0 + c;
    *(short8*)dst       = *(short8*)&o16[0];
    *(short8*)(dst + 8) = *(short8*)&o16[8];
}

// ---------------- kernel 5: bf16 MFMA flash attention, KV-split (flash-decode) ----------------
// Grid (q-tiles, heads, NS_ splits). Each block: 128 queries x 640 keys; writes unnormalized
// partial O~ (bf16) + per-row m,l (f32). Combine kernel merges the NS_ partials.
__global__ __launch_bounds__(256) void attn_mfma_kernel(
    const unsigned short* __restrict__ qh, const unsigned short* __restrict__ kh,
    const unsigned short* __restrict__ vt,
    unsigned short* __restrict__ Opart, float* __restrict__ mpart, float* __restrict__ lpart)
{
    __shared__ __align__(16) short Ks[64 * 128];   // [key][d], 256B rows, slot^=(key&7)
    __shared__ __align__(16) short Vs[128 * 64];   // [d][key], 128B rows, slot^=(d&7)
    int h = blockIdx.y;
    int split = blockIdx.z;
    int t = threadIdx.x;
    int wave = t >> 6, lane = t & 63;
    int l31 = lane & 31, g = lane >> 5;
    int bq = blockIdx.x * 128 + wave * 32;
    const unsigned short* kbase = kh + (size_t)h * SZ_ * HD_;
    const unsigned short* vbase = vt + (size_t)h * HD_ * SZ_;

    short8 qf[8];
    {
        const unsigned short* qb = qh + ((size_t)h * SZ_ + bq + l31) * HD_ + g * 8;
#pragma unroll
        for (int s = 0; s < 8; ++s) qf[s] = *(const short8*)(qb + s * 16);
    }

    f32x16 o[4];
#pragma unroll
    for (int db = 0; db < 4; ++db)
#pragma unroll
        for (int r = 0; r < 16; ++r) o[db][r] = 0.f;
    float mreg = -INFINITY, lreg = 0.f;
    bool qY = (bq >= SX_);
    int sw7 = l31 & 7;
    int ts0 = split * SPL_;

    for (int t0 = ts0; t0 < ts0 + SPL_; t0 += 64) {
        __syncthreads();
        {
            int r = t >> 2, c = t & 3;
            const unsigned short* src = kbase + (size_t)(t0 + r) * HD_ + c * 32;
            short* dst = Ks + r * 128;
            int r7 = r & 7;
#pragma unroll
            for (int j = 0; j < 4; ++j) {
                short8 v = *(const short8*)(src + j * 8);
                int slot = c * 4 + j;
                int sl = (slot & 8) | ((slot ^ r7) & 7);
                *(short8*)(dst + sl * 8) = v;
            }
            int r2 = t >> 1, c2 = t & 1;
            const unsigned short* src2 = vbase + (size_t)r2 * SZ_ + t0 + c2 * 32;
            short* dst2 = Vs + r2 * 64;
            int r27 = r2 & 7;
#pragma unroll
            for (int j = 0; j < 4; ++j) {
                short8 v = *(const short8*)(src2 + j * 8);
                int sl = (c2 * 4 + j) ^ r27;
                *(short8*)(dst2 + sl * 8) = v;
            }
        }
        __syncthreads();

        bool same = (qY == (t0 >= SX_));
        f32x16 sc0, sc1;
#pragma unroll
        for (int r = 0; r < 16; ++r) { sc0[r] = 0.f; sc1[r] = 0.f; }
        const short* Krow0 = Ks + l31 * 128;
        const short* Krow1 = Ks + (l31 + 32) * 128;
#pragma unroll
        for (int s = 4; s < 8; ++s) {
            int slot = 2 * s + g;
            int sl = (slot & 8) | ((slot ^ sw7) & 7);
            sc0 = __builtin_amdgcn_mfma_f32_32x32x16_bf16(*(const short8*)(Krow0 + sl * 8), qf[s], sc0, 0, 0, 0);
            sc1 = __builtin_amdgcn_mfma_f32_32x32x16_bf16(*(const short8*)(Krow1 + sl * 8), qf[s], sc1, 0, 0, 0);
        }
        if (same) {
#pragma unroll
            for (int s = 0; s < 4; ++s) {
                int slot = 2 * s + g;
                int sl = (slot & 8) | ((slot ^ sw7) & 7);
                sc0 = __builtin_amdgcn_mfma_f32_32x32x16_bf16(*(const short8*)(Krow0 + sl * 8), qf[s], sc0, 0, 0, 0);
                sc1 = __builtin_amdgcn_mfma_f32_32x32x16_bf16(*(const short8*)(Krow1 + sl * 8), qf[s], sc1, 0, 0, 0);
            }
        }

        float pm = -INFINITY;
#pragma unroll
        for (int r = 0; r < 16; ++r) pm = fmaxf(pm, fmaxf(sc0[r], sc1[r]));
        pm = fmaxf(pm, __shfl_xor(pm, 32));
        float mnew = fmaxf(mreg, pm);
        float corr = __expf(mreg - mnew);
        mreg = mnew;
        float pp0[16], pp1[16]; float rs = 0.f;
#pragma unroll
        for (int r = 0; r < 16; ++r) {
            pp0[r] = __expf(sc0[r] - mnew);
            pp1[r] = __expf(sc1[r] - mnew);
            rs += pp0[r] + pp1[r];
        }
        rs += __shfl_xor(rs, 32);
        lreg = lreg * corr + rs;
#pragma unroll
        for (int db = 0; db < 4; ++db)
#pragma unroll
            for (int r = 0; r < 16; ++r) o[db][r] *= corr;

        short8 pa0 = mkfrag(&pp0[0]), pa1 = mkfrag(&pp0[8]);
        short8 pa2 = mkfrag(&pp1[0]), pa3 = mkfrag(&pp1[8]);
#pragma unroll
        for (int ks = 0; ks < 4; ++ks) {
            short8 pf = (ks == 0) ? pa0 : (ks == 1) ? pa1 : (ks == 2) ? pa2 : pa3;
#pragma unroll
            for (int db = 0; db < 4; ++db) {
                int row = db * 32 + l31;
                int sl = (2 * ks + g) ^ (l31 & 7);
                const short8 vf = *(const short8*)(Vs + row * 64 + sl * 8);
                o[db] = __builtin_amdgcn_mfma_f32_32x32x16_bf16(vf, pf, o[db], 0, 0, 0);
            }
        }
    }

    // write unnormalized partial
    int basep = ((split * QT_ + blockIdx.x) * H_ + h) * 128 + wave * 32 + l31;
    unsigned short* op = Opart + (size_t)basep * 128;
#pragma unroll
    for (int db = 0; db < 4; ++db)
#pragma unroll
        for (int r = 0; r < 16; ++r) {
            int d = db * 32 + (r & 3) + 8 * (r >> 2) + 4 * g;
            op[d] = f2bf(o[db][r]);
        }
    if (g == 0) { mpart[basep] = mreg; lpart[basep] = lreg; }
}

// ---------------- kernel 5b: combine NS_ partials -> bf16 z ----------------
__global__ __launch_bounds__(256) void attn_combine_kernel(
    const unsigned short* __restrict__ Opart,
    const float* __restrict__ mpart, const float* __restrict__ lpart,
    unsigned short* __restrict__ z)
{
    int t = threadIdx.x;
    int gid = blockIdx.x * 4 + (t >> 6);   // one wave per (q-row, head)
    int lane = t & 63;
    int h = gid & 15;
    int r = gid >> 4;                       // global q row
    int qtile = r >> 7, qi = r & 127;
    int pidx[NS_];
    float m[NS_];
    float mx = -INFINITY;
#pragma unroll
    for (int s = 0; s < NS_; ++s) {
        pidx[s] = ((s * QT_ + qtile) * H_ + h) * 128 + qi;
        m[s] = mpart[pidx[s]];
        mx = fmaxf(mx, m[s]);
    }
    float L = 0.f;
    float w[NS_];
#pragma unroll
    for (int s = 0; s < NS_; ++s) {
        w[s] = __expf(m[s] - mx);
        L += w[s] * lpart[pidx[s]];
    }
    float invL = 1.f / L;
    int d = lane * 2;
    float a0 = 0.f, a1 = 0.f;
#pragma unroll
    for (int s = 0; s < NS_; ++s) {
        unsigned u = *(const unsigned*)(Opart + (size_t)pidx[s] * 128 + d);
        a0 += w[s] * bf2f_lo(u);
        a1 += w[s] * bf2f_hi(u);
    }
    *(unsigned*)(z + (size_t)r * D_ + h * HD_ + d) = pack2(a0 * invL, a1 * invL);
}

extern "C" void kernel_launch(void* const* d_in, const int* in_sizes, int n_in,
                              void* d_out, int out_size, void* d_ws, size_t ws_size,
                              hipStream_t stream) {
    const float* x    = (const float*)d_in[0];
    const float* y    = (const float*)d_in[1];
    const float* mod  = (const float*)d_in[2];
    const float* fx   = (const float*)d_in[3];
    const float* fy   = (const float*)d_in[4];
    const float* Wqx  = (const float*)d_in[7];
    const float* bqx  = (const float*)d_in[8];
    const float* Wqy  = (const float*)d_in[9];
    const float* bqy  = (const float*)d_in[10];
    const float* Wout = (const float*)d_in[11];
    const float* bout = (const float*)d_in[12];
    const float* wq   = (const float*)d_in[13];
    const float* wk   = (const float*)d_in[14];
    const float* Wmq  = (const float*)d_in[15];
    const float* bmq  = (const float*)d_in[16];
    const float* Wmk  = (const float*)d_in[17];
    const float* bmk  = (const float*)d_in[18];

    // workspace layout — total ≈ 142.8 MB
    float* mq   = (float*)d_ws;                              // 6144
    float* mkv  = mq + NQKV_;                                // 6144
    unsigned short* xm   = (unsigned short*)(mkv + NQKV_);   // SZ*D bf16 (later: z)
    unsigned short* qkvb = xm + (size_t)SZ_ * D_;            // SZ*6144 bf16 (later: m/l partials)
    unsigned short* qh   = qkvb + (size_t)SZ_ * NQKV_;       // H*SZ*HD bf16 each
    unsigned short* kh   = qh + (size_t)H_ * SZ_ * HD_;
    unsigned short* vh   = kh + (size_t)H_ * SZ_ * HD_;
    unsigned short* vt   = vh + (size_t)H_ * SZ_ * HD_;
    unsigned short* wqxb = vt + (size_t)H_ * SZ_ * HD_;      // 6144*2048 bf16 (later: O~ partials)
    unsigned short* wqyb = wqxb + (size_t)NQKV_ * D_;
    unsigned short* wob  = wqyb + (size_t)NQKV_ * D_;        // 2048*2048 bf16
    unsigned short* z    = xm;                               // alias: xm dead after QKV GEMM
    // attention partial buffers overlay DEAD regions:
    //   Opart (bf16, NS*20*16*128*128 = 41.9 MB) -> wqxb/wqyb (50.3 MB, dead after QKV GEMM)
    //   mpart/lpart (f32, 0.65 MB each)          -> qkvb      (31.5 MB, dead after qkv_transform)
    unsigned short* Opart = wqxb;
    float* mpart = (float*)qkvb;
    float* lpart = mpart + NS_ * QT_ * H_ * 128;
    float* out  = (float*)d_out;

    hipLaunchKernelGGL(cvt_bf16_kernel, dim3(NQKV_ * D_ / 2048), dim3(256), 0, stream,
                       Wqx, wqxb, NQKV_ * D_);
    hipLaunchKernelGGL(cvt_bf16_kernel, dim3(NQKV_ * D_ / 2048), dim3(256), 0, stream,
                       Wqy, wqyb, NQKV_ * D_);
    hipLaunchKernelGGL(cvt_bf16_kernel, dim3(D_ * D_ / 2048), dim3(256), 0, stream,
                       Wout, wob, D_ * D_);
    hipLaunchKernelGGL(mod_gemv_kernel, dim3(2 * NQKV_ / 4), dim3(256), 0, stream,
                       mod, Wmq, bmq, Wmk, bmk, mq, mkv);
    hipLaunchKernelGGL(ln_mod_kernel, dim3(SZ_), dim3(256), 0, stream,
                       x, y, mq, mkv, xm);
    hipLaunchKernelGGL(gemm_bf16_kernel, dim3(NQKV_ / 128, SZ_ / 128), dim3(256), 0, stream,
                       xm, wqxb, bqx, wqyb, bqy, (void*)qkvb, NQKV_,
                       (const float*)nullptr, (const float*)nullptr,
                       (const float*)nullptr, (const float*)nullptr, 0);
    hipLaunchKernelGGL(qkv_transform_kernel, dim3(SZ_ * H_ / 4), dim3(256), 0, stream,
                       qkvb, fx, fy, wq, wk, qh, kh, vh);
    hipLaunchKernelGGL(vtrans_kernel, dim3(SZ_ / 64, HD_ / 64, H_), dim3(256), 0, stream,
                       vh, vt);
    hipLaunchKernelGGL(attn_mfma_kernel, dim3(QT_, H_, NS_), dim3(256), 0, stream,
                       qh, kh, vt, Opart, mpart, lpart);
    hipLaunchKernelGGL(attn_combine_kernel, dim3(SZ_ * H_ / 4), dim3(256), 0, stream,
                       Opart, mpart, lpart, z);
    hipLaunchKernelGGL(gemm_bf16_kernel, dim3(D_ / 128, SZ_ / 128), dim3(256), 0, stream,
                       z, wob, bout, wob, bout, (void*)out, D_,
                       mq + 2 * D_, mkv + 2 * D_, x, y, 1);
}

// Round 7
// 357.686 us; speedup vs baseline: 7.1952x; 1.1070x over previous
//
#include <hip/hip_runtime.h>
#include <math.h>

// Problem constants (B=1)
#define H_    16
#define DR_   64
#define HD_   128
#define D_    2048
#define SX_   2048
#define SY_   512
#define SZ_   2560
#define NQKV_ 6144          // 3*H*HD
#define EPS_  1e-6f
#define ATTN_SCALE 0.07216878364870323f   // 1/sqrt(2*DR+DN) = 1/sqrt(192)
#define NS_   4             // KV splits (flash-decode)
#define SPL_  (SZ_ / NS_)   // 640 keys per split (multiple of 64)
#define QT_   (SZ_ / 128)   // 20 q-tiles

typedef __attribute__((ext_vector_type(8)))  short short8;   // bf16x8 MFMA frag (4 VGPR)
typedef __attribute__((ext_vector_type(16))) float f32x16;   // 32x32 MFMA accum

__device__ __forceinline__ unsigned short f2bf(float f) {
    unsigned u = __builtin_bit_cast(unsigned, f);
    u += 0x7FFF + ((u >> 16) & 1);          // RNE
    return (unsigned short)(u >> 16);
}
__device__ __forceinline__ unsigned pack2(float a, float b) {
    return (unsigned)f2bf(a) | ((unsigned)f2bf(b) << 16);
}
__device__ __forceinline__ float bf2f_lo(unsigned u) {
    return __builtin_bit_cast(float, u << 16);
}
__device__ __forceinline__ float bf2f_hi(unsigned u) {
    return __builtin_bit_cast(float, u & 0xffff0000u);
}

__device__ __forceinline__ unsigned cvtpk_bf16(float lo, float hi) {
    unsigned r;
    asm volatile("v_cvt_pk_bf16_f32 %0, %1, %2" : "=v"(r) : "v"(lo), "v"(hi));
    return r;
}

// async global->LDS, 16B per lane (dest = wave-uniform base + lane*16)
__device__ __forceinline__ void gload16(const unsigned short* g, unsigned short* l) {
    __builtin_amdgcn_global_load_lds(
        (const __attribute__((address_space(1))) unsigned*)g,
        (__attribute__((address_space(3))) unsigned*)l, 16, 0, 0);
}

// Build PV A/B fragment (16 keys) from 8 per-lane P values (C-reg order) via permlane32_swap.
__device__ __forceinline__ short8 mkfrag(const float* p) {
    unsigned a01 = cvtpk_bf16(p[0], p[1]);
    unsigned a23 = cvtpk_bf16(p[2], p[3]);
    unsigned a45 = cvtpk_bf16(p[4], p[5]);
    unsigned a67 = cvtpk_bf16(p[6], p[7]);
    asm volatile("v_permlane32_swap_b32 %0, %1" : "+v"(a01), "+v"(a45));
    asm volatile("v_permlane32_swap_b32 %0, %1" : "+v"(a23), "+v"(a67));
    union { unsigned u[4]; short8 s; } r;
    r.u[0] = a01; r.u[1] = a23; r.u[2] = a45; r.u[3] = a67;
    return r.s;
}

// ---------------- kernel 0: f32 -> bf16 weight conversion ----------------
__global__ __launch_bounds__(256) void cvt_bf16_kernel(
    const float* __restrict__ src, unsigned short* __restrict__ dst, int n)
{
    int i = (blockIdx.x * 256 + threadIdx.x) * 8;
    if (i >= n) return;
    float4 a = *(const float4*)(src + i);
    float4 b = *(const float4*)(src + i + 4);
    uint4 pk;
    pk.x = pack2(a.x, a.y); pk.y = pack2(a.z, a.w);
    pk.z = pack2(b.x, b.y); pk.w = pack2(b.z, b.w);
    *(uint4*)(dst + i) = pk;
}

// ---------------- kernel 1: modulation GEMV ----------------
__global__ __launch_bounds__(256) void mod_gemv_kernel(
    const float* __restrict__ mod,
    const float* __restrict__ Wq, const float* __restrict__ bq,
    const float* __restrict__ Wkv, const float* __restrict__ bkv,
    float* __restrict__ mq, float* __restrict__ mkv)
{
    int t = threadIdx.x;
    int row = blockIdx.x * 4 + (t >> 6);
    int lane = t & 63;
    const float* W; const float* b; float* out; int r;
    if (row < NQKV_) { W = Wq;  b = bq;  out = mq;  r = row; }
    else             { W = Wkv; b = bkv; out = mkv; r = row - NQKV_; }
    const float* wr = W + (size_t)r * D_;
    float s = 0.f;
    for (int k = lane; k < D_; k += 64) s += wr[k] * mod[k];
#pragma unroll
    for (int m = 32; m >= 1; m >>= 1) s += __shfl_xor(s, m);
    if (lane == 0) out[r] = s + b[r];
}

// ---------------- kernel 2: LayerNorm + modulation, bf16 out ----------------
__global__ __launch_bounds__(256) void ln_mod_kernel(
    const float* __restrict__ x, const float* __restrict__ y,
    const float* __restrict__ mq, const float* __restrict__ mkv,
    unsigned short* __restrict__ xm)
{
    __shared__ float red[8];
    int s = blockIdx.x, t = threadIdx.x;
    const float* src; const float* mv;
    if (s < SX_) { src = x + (size_t)s * D_;          mv = mq; }
    else         { src = y + (size_t)(s - SX_) * D_;  mv = mkv; }
    float a[8];
    *(float4*)&a[0] = *(const float4*)(src + t * 8);
    *(float4*)&a[4] = *(const float4*)(src + t * 8 + 4);
    float sum = 0.f, ssq = 0.f;
#pragma unroll
    for (int i = 0; i < 8; ++i) { sum += a[i]; ssq += a[i] * a[i]; }
#pragma unroll
    for (int m = 32; m >= 1; m >>= 1) { sum += __shfl_xor(sum, m); ssq += __shfl_xor(ssq, m); }
    if ((t & 63) == 0) { red[t >> 6] = sum; red[4 + (t >> 6)] = ssq; }
    __syncthreads();
    float tot  = red[0] + red[1] + red[2] + red[3];
    float totq = red[4] + red[5] + red[6] + red[7];
    float mean = tot * (1.f / (float)D_);
    float var  = totq * (1.f / (float)D_) - mean * mean;
    float inv  = rsqrtf(var + EPS_);
    float o[8];
#pragma unroll
    for (int i = 0; i < 8; ++i) {
        int c = t * 8 + i;
        float v = (a[i] - mean) * inv;
        o[i] = (1.f + mv[D_ + c]) * v + mv[c];
    }
    uint4 pk;
    pk.x = pack2(o[0], o[1]); pk.y = pack2(o[2], o[3]);
    pk.z = pack2(o[4], o[5]); pk.w = pack2(o[6], o[7]);
    *(uint4*)(xm + (size_t)s * D_ + t * 8) = pk;
}

// ---------------- kernel 3: bf16 MFMA GEMM  C = A @ W^T + b ----------------
// 128x128 tile, BK=32, 4 waves (2x2), wave tile 64x64 = 2x2 mfma_32x32x16.
// global_load_lds staging with pre-swizzled source (slot ^= row&3); reads use same XOR.
// mode 0: store bf16. mode 1: store f32 with gate+residual epilogue.
__global__ __launch_bounds__(256) void gemm_bf16_kernel(
    const unsigned short* __restrict__ A,
    const unsigned short* __restrict__ Wx, const float* __restrict__ bx,
    const unsigned short* __restrict__ Wy, const float* __restrict__ by,
    void* __restrict__ Cout, int N,
    const float* __restrict__ gx, const float* __restrict__ gy,
    const float* __restrict__ rx, const float* __restrict__ ry,
    int mode)
{
    __shared__ __align__(16) unsigned short As[128 * 32];
    __shared__ __align__(16) unsigned short Bs[128 * 32];
    int m0 = blockIdx.y * 128, n0 = blockIdx.x * 128;
    const unsigned short* W = (m0 < SX_) ? Wx : Wy;
    const float* bb = (m0 < SX_) ? bx : by;
    int t = threadIdx.x;
    int wv = t >> 6, lane = t & 63, l31 = lane & 31, g = lane >> 5;
    int wr = wv >> 1, wc = wv & 1;
    int srow = t >> 2, ssl = t & 3;
    const unsigned short* gA = A + (size_t)(m0 + srow) * D_ + ((ssl ^ (srow & 3)) * 8);
    const unsigned short* gW = W + (size_t)(n0 + srow) * D_ + ((ssl ^ (srow & 3)) * 8);
    f32x16 acc[2][2];
#pragma unroll
    for (int i = 0; i < 2; ++i)
#pragma unroll
        for (int j = 0; j < 2; ++j)
#pragma unroll
            for (int r = 0; r < 16; ++r) acc[i][j][r] = 0.f;
    int arow = wr * 64 + l31;
    int wrow = wc * 64 + l31;
    int a3 = arow & 3, w3 = wrow & 3;

    for (int k0 = 0; k0 < D_; k0 += 32) {
        __syncthreads();
        gload16(gA + k0,            &As[wv * 512]);
        gload16(gA + 64 * D_ + k0,  &As[2048 + wv * 512]);
        gload16(gW + k0,            &Bs[wv * 512]);
        gload16(gW + 64 * D_ + k0,  &Bs[2048 + wv * 512]);
        __syncthreads();
#pragma unroll
        for (int kk = 0; kk < 2; ++kk) {
            int slot = kk * 2 + g;
            short8 af[2], wf[2];
#pragma unroll
            for (int i = 0; i < 2; ++i) {
                af[i] = *(const short8*)&As[(arow + i * 32) * 32 + ((slot ^ a3) * 8)];
                wf[i] = *(const short8*)&Bs[(wrow + i * 32) * 32 + ((slot ^ w3) * 8)];
            }
#pragma unroll
            for (int i = 0; i < 2; ++i)
#pragma unroll
                for (int j = 0; j < 2; ++j)
                    acc[i][j] = __builtin_amdgcn_mfma_f32_32x32x16_bf16(wf[j], af[i], acc[i][j], 0, 0, 0);
        }
    }

#pragma unroll
    for (int i = 0; i < 2; ++i) {
        int row = m0 + wr * 64 + i * 32 + l31;
        if (mode == 0) {
            unsigned short* C = (unsigned short*)Cout;
#pragma unroll
            for (int j = 0; j < 2; ++j)
#pragma unroll
                for (int q = 0; q < 4; ++q) {
                    int n = n0 + wc * 64 + j * 32 + q * 8 + 4 * g;
                    float o0 = acc[i][j][q * 4 + 0] + bb[n + 0];
                    float o1 = acc[i][j][q * 4 + 1] + bb[n + 1];
                    float o2 = acc[i][j][q * 4 + 2] + bb[n + 2];
                    float o3 = acc[i][j][q * 4 + 3] + bb[n + 3];
                    *(uint2*)(C + (size_t)row * N + n) = make_uint2(pack2(o0, o1), pack2(o2, o3));
                }
        } else {
            float* C = (float*)Cout;
            const float* gt = (row < SX_) ? gx : gy;
            const float* rr = (row < SX_) ? rx + (size_t)row * N : ry + (size_t)(row - SX_) * N;
#pragma unroll
            for (int j = 0; j < 2; ++j)
#pragma unroll
                for (int q = 0; q < 4; ++q) {
                    int n = n0 + wc * 64 + j * 32 + q * 8 + 4 * g;
                    float4 o;
                    o.x = (acc[i][j][q * 4 + 0] + bb[n + 0]) * gt[n + 0] + rr[n + 0];
                    o.y = (acc[i][j][q * 4 + 1] + bb[n + 1]) * gt[n + 1] + rr[n + 1];
                    o.z = (acc[i][j][q * 4 + 2] + bb[n + 2]) * gt[n + 2] + rr[n + 2];
                    o.w = (acc[i][j][q * 4 + 3] + bb[n + 3]) * gt[n + 3] + rr[n + 3];
                    *(float4*)(C + (size_t)row * N + n) = o;
                }
        }
    }
}

// ---------------- kernel 4: RMS + RoPE + head-major transpose (bf16 in/out) ----------------
__global__ __launch_bounds__(256) void qkv_transform_kernel(
    const unsigned short* __restrict__ qkv,
    const float* __restrict__ fx, const float* __restrict__ fy,
    const float* __restrict__ wq, const float* __restrict__ wk,
    unsigned short* __restrict__ qh, unsigned short* __restrict__ kh,
    unsigned short* __restrict__ vh)
{
    int t = threadIdx.x;
    int gid = blockIdx.x * 4 + (t >> 6);
    int lane = t & 63;
    int s = gid >> 4;
    int h = gid & 15;
    const unsigned short* base = qkv + (size_t)s * NQKV_ + h * HD_;
    int d = lane * 2;
    unsigned qu = *(const unsigned*)(base + d);
    unsigned ku = *(const unsigned*)(base + 2048 + d);
    unsigned vu = *(const unsigned*)(base + 4096 + d);
    float qx = bf2f_lo(qu), qy = bf2f_hi(qu);
    float kx = bf2f_lo(ku), ky = bf2f_hi(ku);
    float sq = qx * qx + qy * qy;
    float sk = kx * kx + ky * ky;
#pragma unroll
    for (int m = 32; m >= 1; m >>= 1) { sq += __shfl_xor(sq, m); sk += __shfl_xor(sk, m); }
    float qs = rsqrtf(sq * (1.f / 128.f) + EPS_) * ATTN_SCALE;
    float ks = rsqrtf(sk * (1.f / 128.f) + EPS_);
    float q0 = qx * qs * wq[d], q1 = qy * qs * wq[d + 1];
    float k0 = kx * ks * wk[d], k1 = ky * ks * wk[d + 1];
    if (lane < 32) {
        const float* f = (s < SX_) ? fx + (size_t)s * DR_ + d
                                   : fy + (size_t)(s - SX_) * DR_ + d;
        float cs = f[0], sn = f[1];
        float o0 = q0 * cs - q1 * sn, o1 = q0 * sn + q1 * cs;
        q0 = o0; q1 = o1;
        o0 = k0 * cs - k1 * sn; o1 = k0 * sn + k1 * cs;
        k0 = o0; k1 = o1;
    }
    size_t off = ((size_t)h * SZ_ + s) * HD_ + d;
    *(unsigned*)(qh + off) = pack2(q0, q1);
    *(unsigned*)(kh + off) = pack2(k0, k1);
    *(unsigned*)(vh + off) = vu;
}

// ---------------- kernel 4b: V transpose per head: vh[h][s][d] -> vt[h][d][s] ----------------
__global__ __launch_bounds__(256) void vtrans_kernel(
    const unsigned short* __restrict__ vh, unsigned short* __restrict__ vt)
{
    __shared__ __align__(16) unsigned short T[64][72];
    int h = blockIdx.z, d0 = blockIdx.y * 64, s0 = blockIdx.x * 64;
    int t = threadIdx.x;
    int r = t >> 2, c = (t & 3) * 16;
    const unsigned short* src = vh + ((size_t)h * SZ_ + s0 + r) * HD_ + d0 + c;
    *(short8*)&T[r][c]     = *(const short8*)(src);
    *(short8*)&T[r][c + 8] = *(const short8*)(src + 8);
    __syncthreads();
    unsigned short o16[16];
#pragma unroll
    for (int i = 0; i < 16; ++i) o16[i] = T[c + i][r];
    unsigned short* dst = vt + ((size_t)h * HD_ + d0 + r) * SZ_ + s0 + c;
    *(short8*)dst       = *(short8*)&o16[0];
    *(short8*)(dst + 8) = *(short8*)&o16[8];
}

// ---------------- kernel 5: bf16 MFMA flash attention, KV-split + double-buffered gload_lds ------
// Grid (q-tiles, heads, NS_ splits). Staging: global_load_lds width16, linear LDS dest,
// pre-swizzled per-lane global source (same XOR involution as the read side — rule 21).
// Next tile's loads issued BEFORE current tile's compute; __syncthreads drains vmcnt (T3 2-phase).
__global__ __launch_bounds__(256) void attn_mfma_kernel(
    const unsigned short* __restrict__ qh, const unsigned short* __restrict__ kh,
    const unsigned short* __restrict__ vt,
    unsigned short* __restrict__ Opart, float* __restrict__ mpart, float* __restrict__ lpart)
{
    __shared__ __align__(16) short Ks[2][64 * 128];   // [key][d], 256B rows, slot swizzled
    __shared__ __align__(16) short Vs[2][128 * 64];   // [d][key], 128B rows, slot swizzled
    int h = blockIdx.y;
    int split = blockIdx.z;
    int t = threadIdx.x;
    int wv = t >> 6, lane = t & 63;
    int l31 = lane & 31, g = lane >> 5;
    int bq = blockIdx.x * 128 + wv * 32;
    const unsigned short* kbase = kh + (size_t)h * SZ_ * HD_;
    const unsigned short* vbase = vt + (size_t)h * HD_ * SZ_;

    // per-lane pre-swizzled source offsets (shorts). Chunk idx = i*256 + t covers the 16KB tile.
    // K: LDS position (r, sl) holds global slot (sl&8)|((sl^(r&7))&7)  [involution]
    // V: LDS position (r2, sl2) holds global slot sl2^(r2&7)
    int koff[4], voff[4];
#pragma unroll
    for (int i = 0; i < 4; ++i) {
        int idx = i * 256 + t;
        int r = idx >> 4, sl = idx & 15;
        koff[i] = r * HD_ + (((sl & 8) | ((sl ^ (r & 7)) & 7)) * 8);
        int r2 = idx >> 3, sl2 = idx & 7;
        voff[i] = r2 * SZ_ + ((sl2 ^ (r2 & 7)) * 8);
    }
    int ldsOff = wv * 512;   // shorts; + i*2048 per chunk-iteration; lane*16B added by HW

    short8 qf[8];
    {
        const unsigned short* qb = qh + ((size_t)h * SZ_ + bq + l31) * HD_ + g * 8;
#pragma unroll
        for (int s = 0; s < 8; ++s) qf[s] = *(const short8*)(qb + s * 16);
    }

    f32x16 o[4];
#pragma unroll
    for (int db = 0; db < 4; ++db)
#pragma unroll
        for (int r = 0; r < 16; ++r) o[db][r] = 0.f;
    float mreg = -INFINITY, lreg = 0.f;
    bool qY = (bq >= SX_);
    int sw7 = l31 & 7;
    int ts0 = split * SPL_;
    const int NT = SPL_ / 64;   // 10

    // prologue: stage tile 0 into buffer 0
#pragma unroll
    for (int i = 0; i < 4; ++i)
        gload16(kbase + (size_t)ts0 * HD_ + koff[i], (unsigned short*)&Ks[0][0] + i * 2048 + ldsOff);
#pragma unroll
    for (int i = 0; i < 4; ++i)
        gload16(vbase + ts0 + voff[i], (unsigned short*)&Vs[0][0] + i * 2048 + ldsOff);
    __syncthreads();   // drains vmcnt(0) before barrier

    for (int it = 0; it < NT; ++it) {
        int t0 = ts0 + it * 64;
        int cur = it & 1;
        if (it + 1 < NT) {        // prefetch next tile into the other buffer (async)
            int nb = cur ^ 1;
            const unsigned short* kn = kbase + (size_t)(t0 + 64) * HD_;
            const unsigned short* vn = vbase + (t0 + 64);
#pragma unroll
            for (int i = 0; i < 4; ++i)
                gload16(kn + koff[i], (unsigned short*)&Ks[nb][0] + i * 2048 + ldsOff);
#pragma unroll
            for (int i = 0; i < 4; ++i)
                gload16(vn + voff[i], (unsigned short*)&Vs[nb][0] + i * 2048 + ldsOff);
        }

        bool same = (qY == (t0 >= SX_));
        f32x16 sc0, sc1;
#pragma unroll
        for (int r = 0; r < 16; ++r) { sc0[r] = 0.f; sc1[r] = 0.f; }
        const short* Krow0 = &Ks[cur][0] + l31 * 128;
        const short* Krow1 = &Ks[cur][0] + (l31 + 32) * 128;
        __builtin_amdgcn_s_setprio(1);
#pragma unroll
        for (int s = 4; s < 8; ++s) {       // nope dims always
            int slot = 2 * s + g;
            int sl = (slot & 8) | ((slot ^ sw7) & 7);
            sc0 = __builtin_amdgcn_mfma_f32_32x32x16_bf16(*(const short8*)(Krow0 + sl * 8), qf[s], sc0, 0, 0, 0);
            sc1 = __builtin_amdgcn_mfma_f32_32x32x16_bf16(*(const short8*)(Krow1 + sl * 8), qf[s], sc1, 0, 0, 0);
        }
        if (same) {
#pragma unroll
            for (int s = 0; s < 4; ++s) {   // rope dims only for same-modality
                int slot = 2 * s + g;
                int sl = (slot & 8) | ((slot ^ sw7) & 7);
                sc0 = __builtin_amdgcn_mfma_f32_32x32x16_bf16(*(const short8*)(Krow0 + sl * 8), qf[s], sc0, 0, 0, 0);
                sc1 = __builtin_amdgcn_mfma_f32_32x32x16_bf16(*(const short8*)(Krow1 + sl * 8), qf[s], sc1, 0, 0, 0);
            }
        }
        __builtin_amdgcn_s_setprio(0);

        float pm = -INFINITY;
#pragma unroll
        for (int r = 0; r < 16; ++r) pm = fmaxf(pm, fmaxf(sc0[r], sc1[r]));
        pm = fmaxf(pm, __shfl_xor(pm, 32));
        float mnew = fmaxf(mreg, pm);
        float corr = __expf(mreg - mnew);
        mreg = mnew;
        float pp0[16], pp1[16]; float rs = 0.f;
#pragma unroll
        for (int r = 0; r < 16; ++r) {
            pp0[r] = __expf(sc0[r] - mnew);
            pp1[r] = __expf(sc1[r] - mnew);
            rs += pp0[r] + pp1[r];
        }
        rs += __shfl_xor(rs, 32);
        lreg = lreg * corr + rs;
#pragma unroll
        for (int db = 0; db < 4; ++db)
#pragma unroll
            for (int r = 0; r < 16; ++r) o[db][r] *= corr;

        short8 pa0 = mkfrag(&pp0[0]), pa1 = mkfrag(&pp0[8]);
        short8 pa2 = mkfrag(&pp1[0]), pa3 = mkfrag(&pp1[8]);
        const short* Vb = &Vs[cur][0];
        __builtin_amdgcn_s_setprio(1);
#pragma unroll
        for (int ks = 0; ks < 4; ++ks) {
            short8 pf = (ks == 0) ? pa0 : (ks == 1) ? pa1 : (ks == 2) ? pa2 : pa3;
#pragma unroll
            for (int db = 0; db < 4; ++db) {
                int row = db * 32 + l31;
                int sl = (2 * ks + g) ^ (l31 & 7);
                const short8 vf = *(const short8*)(Vb + row * 64 + sl * 8);
                o[db] = __builtin_amdgcn_mfma_f32_32x32x16_bf16(vf, pf, o[db], 0, 0, 0);
            }
        }
        __builtin_amdgcn_s_setprio(0);
        __syncthreads();   // compiler emits vmcnt(0) lgkmcnt(0) drain — prefetch landed
    }

    // write unnormalized partial
    int basep = ((split * QT_ + blockIdx.x) * H_ + h) * 128 + wv * 32 + l31;
    unsigned short* op = Opart + (size_t)basep * 128;
#pragma unroll
    for (int db = 0; db < 4; ++db)
#pragma unroll
        for (int r = 0; r < 16; ++r) {
            int d = db * 32 + (r & 3) + 8 * (r >> 2) + 4 * g;
            op[d] = f2bf(o[db][r]);
        }
    if (g == 0) { mpart[basep] = mreg; lpart[basep] = lreg; }
}

// ---------------- kernel 5b: combine NS_ partials -> bf16 z ----------------
__global__ __launch_bounds__(256) void attn_combine_kernel(
    const unsigned short* __restrict__ Opart,
    const float* __restrict__ mpart, const float* __restrict__ lpart,
    unsigned short* __restrict__ z)
{
    int t = threadIdx.x;
    int gid = blockIdx.x * 4 + (t >> 6);   // one wave per (q-row, head)
    int lane = t & 63;
    int h = gid & 15;
    int r = gid >> 4;                       // global q row
    int qtile = r >> 7, qi = r & 127;
    int pidx[NS_];
    float m[NS_];
    float mx = -INFINITY;
#pragma unroll
    for (int s = 0; s < NS_; ++s) {
        pidx[s] = ((s * QT_ + qtile) * H_ + h) * 128 + qi;
        m[s] = mpart[pidx[s]];
        mx = fmaxf(mx, m[s]);
    }
    float L = 0.f;
    float w[NS_];
#pragma unroll
    for (int s = 0; s < NS_; ++s) {
        w[s] = __expf(m[s] - mx);
        L += w[s] * lpart[pidx[s]];
    }
    float invL = 1.f / L;
    int d = lane * 2;
    float a0 = 0.f, a1 = 0.f;
#pragma unroll
    for (int s = 0; s < NS_; ++s) {
        unsigned u = *(const unsigned*)(Opart + (size_t)pidx[s] * 128 + d);
        a0 += w[s] * bf2f_lo(u);
        a1 += w[s] * bf2f_hi(u);
    }
    *(unsigned*)(z + (size_t)r * D_ + h * HD_ + d) = pack2(a0 * invL, a1 * invL);
}

extern "C" void kernel_launch(void* const* d_in, const int* in_sizes, int n_in,
                              void* d_out, int out_size, void* d_ws, size_t ws_size,
                              hipStream_t stream) {
    const float* x    = (const float*)d_in[0];
    const float* y    = (const float*)d_in[1];
    const float* mod  = (const float*)d_in[2];
    const float* fx   = (const float*)d_in[3];
    const float* fy   = (const float*)d_in[4];
    const float* Wqx  = (const float*)d_in[7];
    const float* bqx  = (const float*)d_in[8];
    const float* Wqy  = (const float*)d_in[9];
    const float* bqy  = (const float*)d_in[10];
    const float* Wout = (const float*)d_in[11];
    const float* bout = (const float*)d_in[12];
    const float* wq   = (const float*)d_in[13];
    const float* wk   = (const float*)d_in[14];
    const float* Wmq  = (const float*)d_in[15];
    const float* bmq  = (const float*)d_in[16];
    const float* Wmk  = (const float*)d_in[17];
    const float* bmk  = (const float*)d_in[18];

    // workspace layout — total ≈ 142.8 MB
    float* mq   = (float*)d_ws;                              // 6144
    float* mkv  = mq + NQKV_;                                // 6144
    unsigned short* xm   = (unsigned short*)(mkv + NQKV_);   // SZ*D bf16 (later: z)
    unsigned short* qkvb = xm + (size_t)SZ_ * D_;            // SZ*6144 bf16 (later: m/l partials)
    unsigned short* qh   = qkvb + (size_t)SZ_ * NQKV_;       // H*SZ*HD bf16 each
    unsigned short* kh   = qh + (size_t)H_ * SZ_ * HD_;
    unsigned short* vh   = kh + (size_t)H_ * SZ_ * HD_;
    unsigned short* vt   = vh + (size_t)H_ * SZ_ * HD_;
    unsigned short* wqxb = vt + (size_t)H_ * SZ_ * HD_;      // 6144*2048 bf16 (later: O~ partials)
    unsigned short* wqyb = wqxb + (size_t)NQKV_ * D_;
    unsigned short* wob  = wqyb + (size_t)NQKV_ * D_;        // 2048*2048 bf16
    unsigned short* z    = xm;                               // alias: xm dead after QKV GEMM
    // attention partial buffers overlay DEAD regions:
    //   Opart (bf16, NS*20*16*128*128 = 41.9 MB) -> wqxb/wqyb (50.3 MB, dead after QKV GEMM)
    //   mpart/lpart (f32, 0.65 MB each)          -> qkvb      (31.5 MB, dead after qkv_transform)
    unsigned short* Opart = wqxb;
    float* mpart = (float*)qkvb;
    float* lpart = mpart + NS_ * QT_ * H_ * 128;
    float* out  = (float*)d_out;

    hipLaunchKernelGGL(cvt_bf16_kernel, dim3(NQKV_ * D_ / 2048), dim3(256), 0, stream,
                       Wqx, wqxb, NQKV_ * D_);
    hipLaunchKernelGGL(cvt_bf16_kernel, dim3(NQKV_ * D_ / 2048), dim3(256), 0, stream,
                       Wqy, wqyb, NQKV_ * D_);
    hipLaunchKernelGGL(cvt_bf16_kernel, dim3(D_ * D_ / 2048), dim3(256), 0, stream,
                       Wout, wob, D_ * D_);
    hipLaunchKernelGGL(mod_gemv_kernel, dim3(2 * NQKV_ / 4), dim3(256), 0, stream,
                       mod, Wmq, bmq, Wmk, bmk, mq, mkv);
    hipLaunchKernelGGL(ln_mod_kernel, dim3(SZ_), dim3(256), 0, stream,
                       x, y, mq, mkv, xm);
    hipLaunchKernelGGL(gemm_bf16_kernel, dim3(NQKV_ / 128, SZ_ / 128), dim3(256), 0, stream,
                       xm, wqxb, bqx, wqyb, bqy, (void*)qkvb, NQKV_,
                       (const float*)nullptr, (const float*)nullptr,
                       (const float*)nullptr, (const float*)nullptr, 0);
    hipLaunchKernelGGL(qkv_transform_kernel, dim3(SZ_ * H_ / 4), dim3(256), 0, stream,
                       qkvb, fx, fy, wq, wk, qh, kh, vh);
    hipLaunchKernelGGL(vtrans_kernel, dim3(SZ_ / 64, HD_ / 64, H_), dim3(256), 0, stream,
                       vh, vt);
    hipLaunchKernelGGL(attn_mfma_kernel, dim3(QT_, H_, NS_), dim3(256), 0, stream,
                       qh, kh, vt, Opart, mpart, lpart);
    hipLaunchKernelGGL(attn_combine_kernel, dim3(SZ_ * H_ / 4), dim3(256), 0, stream,
                       Opart, mpart, lpart, z);
    hipLaunchKernelGGL(gemm_bf16_kernel, dim3(D_ / 128, SZ_ / 128), dim3(256), 0, stream,
                       z, wob, bout, wob, bout, (void*)out, D_,
                       mq + 2 * D_, mkv + 2 * D_, x, y, 1);
}